// Round 2
// baseline (831.079 us; speedup 1.0000x reference)
//
#include <hip/hip_runtime.h>

// Problem constants (fixed by harness)
#define DD 512      // feature dim d
#define MM 256      // random features m
#define BB 8
#define LL 2048
#define KLT 8192    // K*L style rows per batch

__device__ __constant__ const float S1 = 0.21022410381342864f;   // 512^-0.25
__device__ __constant__ const float INV2SD = 0.02209708691207961f; // 1/(2*sqrt(512))
__device__ __constant__ const float S2 = 0.0625f;                 // 256^-0.5
#define EPSV 1e-8f

// ---------------- sq[r] = sum(x^2)/(2 sqrt(d)) ; one wave per row ----------------
__global__ __launch_bounds__(256) void sq_kernel(const float* __restrict__ X,
                                                 float* __restrict__ Sq) {
    int row  = blockIdx.x * 4 + (threadIdx.x >> 6);
    int lane = threadIdx.x & 63;
    const float4* xr = (const float4*)(X + (size_t)row * DD);
    float s = 0.f;
#pragma unroll
    for (int i = 0; i < 2; ++i) {      // 128 float4 per row, 64 lanes
        float4 v = xr[lane + i * 64];
        s += v.x * v.x + v.y * v.y + v.z * v.z + v.w * v.w;
    }
#pragma unroll
    for (int off = 32; off; off >>= 1) s += __shfl_down(s, off);
    if (lane == 0) Sq[row] = s * INV2SD;
}

// ------------- phi GEMM: Phi[r,c] = exp((X[r,:]·W[:,c])*S1 - sq[r]) * S2 -------------
// 64x64 tile, BK=32, 256 threads, 4x4 micro-tile.
__global__ __launch_bounds__(256) void phi_gemm(const float* __restrict__ X,
                                                const float* __restrict__ Wm,
                                                const float* __restrict__ Sq,
                                                float* __restrict__ Phi) {
    __shared__ float As[32][68];   // [k][row], pad 68 keeps b128 reads 16B-aligned
    __shared__ float Bs[32][64];   // [k][col]
    const int rb = blockIdx.x * 64;
    const int cb = blockIdx.y * 64;
    const int tid = threadIdx.x;
    const int tx = tid & 15, ty = tid >> 4;
    float acc[4][4] = {};
    for (int k0 = 0; k0 < DD; k0 += 32) {
#pragma unroll
        for (int i = 0; i < 2; ++i) {           // A tile 64x32, transposed store
            int f = tid + i * 256;
            int r = f >> 3, c4 = f & 7;
            float4 v = *(const float4*)(X + (size_t)(rb + r) * DD + k0 + c4 * 4);
            As[c4 * 4 + 0][r] = v.x; As[c4 * 4 + 1][r] = v.y;
            As[c4 * 4 + 2][r] = v.z; As[c4 * 4 + 3][r] = v.w;
        }
#pragma unroll
        for (int i = 0; i < 2; ++i) {           // B tile 32x64 from W [512,256]
            int f = tid + i * 256;
            int r = f >> 4, c4 = f & 15;
            *(float4*)&Bs[r][c4 * 4] =
                *(const float4*)(Wm + (size_t)(k0 + r) * MM + cb + c4 * 4);
        }
        __syncthreads();
#pragma unroll
        for (int kk = 0; kk < 32; ++kk) {
            float4 av = *(const float4*)&As[kk][ty * 4];
            float4 bv = *(const float4*)&Bs[kk][tx * 4];
            float a[4] = {av.x, av.y, av.z, av.w};
            float b[4] = {bv.x, bv.y, bv.z, bv.w};
#pragma unroll
            for (int i2 = 0; i2 < 4; ++i2)
#pragma unroll
                for (int j = 0; j < 4; ++j) acc[i2][j] += a[i2] * b[j];
        }
        __syncthreads();
    }
#pragma unroll
    for (int i2 = 0; i2 < 4; ++i2) {
        int r = rb + ty * 4 + i2;
        float sv = Sq[r];
#pragma unroll
        for (int j = 0; j < 4; ++j)
            Phi[(size_t)r * MM + cb + tx * 4 + j] =
                expf(acc[i2][j] * S1 - sv) * S2;
    }
}

// ---------------- Z[b,m] = sum_kl PhiK[b,kl,m] ----------------
__global__ __launch_bounds__(256) void z_kernel(const float* __restrict__ PhiK,
                                                float* __restrict__ Z) {
    int b = blockIdx.y;
    int m = threadIdx.x;
    int kl0 = blockIdx.x * 256;
    const float* p = PhiK + ((size_t)b * KLT + kl0) * MM + m;
    float s = 0.f;
    for (int i = 0; i < 256; ++i) s += p[(size_t)i * MM];
    atomicAdd(&Z[b * MM + m], s);
}

// ------------- S[b,m,d] = sum_kl PhiK[b,kl,m] * Style[b,kl,d]; split-K=4, atomic -------------
__global__ __launch_bounds__(256) void s_gemm(const float* __restrict__ PhiK,
                                              const float* __restrict__ Style,
                                              float* __restrict__ S) {
    __shared__ float As[32][64];   // [k][m] (natural layout of phi_k rows)
    __shared__ float Bs[32][64];   // [k][d]
    const int b = blockIdx.z >> 2;
    const int split = blockIdx.z & 3;
    const int mb = blockIdx.x * 64;
    const int db = blockIdx.y * 64;
    const float* A0 = PhiK + (size_t)b * KLT * MM;
    const float* B0 = Style + (size_t)b * KLT * DD;
    const int tid = threadIdx.x, tx = tid & 15, ty = tid >> 4;
    float acc[4][4] = {};
    const int kend = split * 2048 + 2048;
    for (int k0 = split * 2048; k0 < kend; k0 += 32) {
#pragma unroll
        for (int i = 0; i < 2; ++i) {
            int f = tid + i * 256;
            int r = f >> 4, c4 = f & 15;
            *(float4*)&As[r][c4 * 4] =
                *(const float4*)(A0 + (size_t)(k0 + r) * MM + mb + c4 * 4);
            *(float4*)&Bs[r][c4 * 4] =
                *(const float4*)(B0 + (size_t)(k0 + r) * DD + db + c4 * 4);
        }
        __syncthreads();
#pragma unroll
        for (int kk = 0; kk < 32; ++kk) {
            float4 av = *(const float4*)&As[kk][ty * 4];
            float4 bv = *(const float4*)&Bs[kk][tx * 4];
            float a[4] = {av.x, av.y, av.z, av.w};
            float bvv[4] = {bv.x, bv.y, bv.z, bv.w};
#pragma unroll
            for (int i2 = 0; i2 < 4; ++i2)
#pragma unroll
                for (int j = 0; j < 4; ++j) acc[i2][j] += a[i2] * bvv[j];
        }
        __syncthreads();
    }
#pragma unroll
    for (int i2 = 0; i2 < 4; ++i2)
#pragma unroll
        for (int j = 0; j < 4; ++j)
            atomicAdd(&S[((size_t)b * MM + mb + ty * 4 + i2) * DD + db + tx * 4 + j],
                      acc[i2][j]);
}

// ---------------- den[b,l] = phi_q[b,l,:]·Z[b,:] ; one wave per row ----------------
__global__ __launch_bounds__(256) void den_kernel(const float* __restrict__ PhiQ,
                                                  const float* __restrict__ Z,
                                                  float* __restrict__ Den) {
    int row  = blockIdx.x * 4 + (threadIdx.x >> 6);   // flat b*L + l
    int lane = threadIdx.x & 63;
    int b = row >> 11;                                 // 2048 rows per batch
    const float4* pq = (const float4*)(PhiQ + (size_t)row * MM);
    const float4* pz = (const float4*)(Z + (size_t)b * MM);
    float4 q = pq[lane];
    float4 z = pz[lane];
    float s = q.x * z.x + q.y * z.y + q.z * z.z + q.w * z.w;
#pragma unroll
    for (int off = 32; off; off >>= 1) s += __shfl_down(s, off);
    if (lane == 0) Den[row] = s;
}

// ------------- out: num = PhiQ·S ; f = num/(den+eps); amp = content + f -------------
__global__ __launch_bounds__(256) void out_gemm(const float* __restrict__ PhiQ,
                                                const float* __restrict__ Sb,
                                                const float* __restrict__ Den,
                                                const float* __restrict__ Content,
                                                float* __restrict__ Amp,
                                                float* __restrict__ Fa) {
    __shared__ float As[32][68];
    __shared__ float Bs[32][64];
    const int b = blockIdx.z;
    const int rb = blockIdx.x * 64;   // l-tile
    const int db = blockIdx.y * 64;   // d-tile
    const float* A0 = PhiQ + (size_t)b * LL * MM;
    const float* B0 = Sb + (size_t)b * MM * DD;
    const int tid = threadIdx.x, tx = tid & 15, ty = tid >> 4;
    float acc[4][4] = {};
    for (int k0 = 0; k0 < MM; k0 += 32) {
#pragma unroll
        for (int i = 0; i < 2; ++i) {
            int f = tid + i * 256;
            int r = f >> 3, c4 = f & 7;
            float4 v = *(const float4*)(A0 + (size_t)(rb + r) * MM + k0 + c4 * 4);
            As[c4 * 4 + 0][r] = v.x; As[c4 * 4 + 1][r] = v.y;
            As[c4 * 4 + 2][r] = v.z; As[c4 * 4 + 3][r] = v.w;
        }
#pragma unroll
        for (int i = 0; i < 2; ++i) {
            int f = tid + i * 256;
            int r = f >> 4, c4 = f & 15;
            *(float4*)&Bs[r][c4 * 4] =
                *(const float4*)(B0 + (size_t)(k0 + r) * DD + db + c4 * 4);
        }
        __syncthreads();
#pragma unroll
        for (int kk = 0; kk < 32; ++kk) {
            float4 av = *(const float4*)&As[kk][ty * 4];
            float4 bv = *(const float4*)&Bs[kk][tx * 4];
            float a[4] = {av.x, av.y, av.z, av.w};
            float bvv[4] = {bv.x, bv.y, bv.z, bv.w};
#pragma unroll
            for (int i2 = 0; i2 < 4; ++i2)
#pragma unroll
                for (int j = 0; j < 4; ++j) acc[i2][j] += a[i2] * bvv[j];
        }
        __syncthreads();
    }
#pragma unroll
    for (int i2 = 0; i2 < 4; ++i2) {
        int r = rb + ty * 4 + i2;
        float inv = 1.0f / (Den[(size_t)b * LL + r] + EPSV);
#pragma unroll
        for (int j = 0; j < 4; ++j) {
            size_t idx = ((size_t)b * LL + r) * DD + db + tx * 4 + j;
            float f = acc[i2][j] * inv;
            Fa[idx] = f;
            Amp[idx] = Content[idx] + f;
        }
    }
}

extern "C" void kernel_launch(void* const* d_in, const int* in_sizes, int n_in,
                              void* d_out, int out_size, void* d_ws, size_t ws_size,
                              hipStream_t stream) {
    const float* content = (const float*)d_in[0];   // [8,2048,512]
    const float* style   = (const float*)d_in[1];   // [8,4,2048,512]
    const float* Wm      = (const float*)d_in[2];   // [512,256]
    float* amp = (float*)d_out;                       // [8,2048,512]
    float* fa  = (float*)d_out + (size_t)BB * LL * DD;

    // workspace layout (floats)
    float* ws    = (float*)d_ws;
    float* phi_k = ws;                                  // 8*8192*256 = 16,777,216
    float* phi_q = phi_k + (size_t)BB * KLT * MM;       //  8*2048*256 = 4,194,304
    float* sq_k  = phi_q + (size_t)BB * LL * MM;        // 65,536
    float* sq_q  = sq_k + (size_t)BB * KLT;             // 16,384
    float* Sbuf  = sq_q + (size_t)BB * LL;              // 8*256*512 = 1,048,576
    float* Zbuf  = Sbuf + (size_t)BB * MM * DD;         // 2,048
    float* den   = Zbuf + (size_t)BB * MM;              // 16,384

    // zero accumulation targets (S and Z are contiguous)
    hipMemsetAsync(Sbuf, 0, ((size_t)BB * MM * DD + BB * MM) * sizeof(float), stream);

    sq_kernel<<<(BB * KLT) / 4, 256, 0, stream>>>(style, sq_k);
    sq_kernel<<<(BB * LL) / 4, 256, 0, stream>>>(content, sq_q);

    phi_gemm<<<dim3((BB * KLT) / 64, MM / 64), 256, 0, stream>>>(style, Wm, sq_k, phi_k);
    phi_gemm<<<dim3((BB * LL) / 64, MM / 64), 256, 0, stream>>>(content, Wm, sq_q, phi_q);

    z_kernel<<<dim3(KLT / 256, BB), 256, 0, stream>>>(phi_k, Zbuf);
    s_gemm<<<dim3(MM / 64, DD / 64, BB * 4), 256, 0, stream>>>(phi_k, style, Sbuf);

    den_kernel<<<(BB * LL) / 4, 256, 0, stream>>>(phi_q, Zbuf, den);
    out_gemm<<<dim3(LL / 64, DD / 64, BB), 256, 0, stream>>>(phi_q, Sbuf, den, content, amp, fa);
}

// Round 3
// 465.501 us; speedup vs baseline: 1.7853x; 1.7853x over previous
//
#include <hip/hip_runtime.h>
#include <hip/hip_bf16.h>
#include <math.h>

typedef short  s16x8 __attribute__((ext_vector_type(8)));
typedef float  f32x4 __attribute__((ext_vector_type(4)));

#define DD 512      // feature dim d
#define MM 256      // random features m
#define BB 8
#define LL 2048
#define KLT 8192    // K*L style rows per batch

#define S1f     0.21022410381342864f   // 512^-0.25
#define INV2SDf 0.02209708691207961f   // 1/(2*sqrt(512))
#define S2f     0.0625f                // 256^-0.5
#define EPSV    1e-8f

__device__ __forceinline__ ushort f2b(float f) {
    __hip_bfloat16 h = __float2bfloat16(f);
    return *reinterpret_cast<ushort*>(&h);
}
__device__ __forceinline__ float b2f(ushort u) {
    union { unsigned u32; float f; } x; x.u32 = ((unsigned)u) << 16; return x.f;
}

// ---------- convert fp32 -> bf16, and per-row sq = sum(x^2)/(2 sqrt d) ----------
// grid: rows/64 blocks of 256. Each thread: one quarter-row (128 floats).
__global__ __launch_bounds__(256) void convert_kernel(const float* __restrict__ X,
                                                      ushort* __restrict__ Xb,
                                                      float* __restrict__ Sq) {
    const int t = threadIdx.x;
    const int r = blockIdx.x * 64 + (t >> 2);
    const int q = t & 3;
    const float4* src = (const float4*)(X + (size_t)r * DD + q * 128);
    ushort* dst = Xb + (size_t)r * DD + q * 128;
    float s = 0.f;
#pragma unroll
    for (int i = 0; i < 16; ++i) {
        float4 v0 = src[2 * i], v1 = src[2 * i + 1];
        s += v0.x * v0.x + v0.y * v0.y + v0.z * v0.z + v0.w * v0.w
           + v1.x * v1.x + v1.y * v1.y + v1.z * v1.z + v1.w * v1.w;
        s16x8 o;
        o[0] = (short)f2b(v0.x); o[1] = (short)f2b(v0.y);
        o[2] = (short)f2b(v0.z); o[3] = (short)f2b(v0.w);
        o[4] = (short)f2b(v1.x); o[5] = (short)f2b(v1.y);
        o[6] = (short)f2b(v1.z); o[7] = (short)f2b(v1.w);
        *(s16x8*)(dst + 8 * i) = o;
    }
    s += __shfl_xor(s, 1);
    s += __shfl_xor(s, 2);
    if (q == 0) Sq[r] = s * INV2SDf;
}

// ---------- Wt[m][d] = bf16(W[d][m]) ; 64x64 LDS tile transpose ----------
__global__ __launch_bounds__(256) void prep_w(const float* __restrict__ W,
                                              ushort* __restrict__ Wt) {
    __shared__ ushort lds[64 * 78];
    const int t = threadIdx.x;
    const int dt = blockIdx.x;   // 0..7
    const int mt = blockIdx.y;   // 0..3
    {
        int r = t >> 2, c0 = (t & 3) * 16;   // r: d-local, c: m-local
        const float4* src = (const float4*)(W + (size_t)(dt * 64 + r) * MM + mt * 64 + c0);
#pragma unroll
        for (int i = 0; i < 4; ++i) {
            float4 v = src[i];
            lds[r * 78 + c0 + 4 * i + 0] = f2b(v.x);
            lds[r * 78 + c0 + 4 * i + 1] = f2b(v.y);
            lds[r * 78 + c0 + 4 * i + 2] = f2b(v.z);
            lds[r * 78 + c0 + 4 * i + 3] = f2b(v.w);
        }
    }
    __syncthreads();
    {
        int m = t >> 2, d0 = (t & 3) * 16;
        ushort* dst = Wt + (size_t)(mt * 64 + m) * DD + dt * 64 + d0;
#pragma unroll
        for (int j = 0; j < 16; ++j) dst[j] = lds[(d0 + j) * 78 + m];
    }
}

// ---------- unified 128x128 BK=32 bf16 MFMA core ----------
// A: [rows][K] bf16 row-major (lda).  B (BT=false): [cols][K] bf16 row-major (ldb)
// — i.e. the operand whose rows are output-columns, k-contiguous.
// B (BT=true): [K][cols] bf16 row-major (ldb) — transposed during LDS staging.
template <bool BT>
__device__ __forceinline__ void gemm128(const ushort* __restrict__ A, int lda,
                                        const ushort* __restrict__ B, int ldb,
                                        int rowbase, int colbase, int k0, int k1,
                                        ushort* sA, ushort* sB, f32x4 acc[4][4]) {
    const int t = threadIdx.x;
    const int l = t & 63, w = t >> 6;
    const int wr = (w >> 1) * 64, wc = (w & 1) * 64;
    const int fr = l & 15, fg = l >> 4;
    const int srow = t >> 1, shalf = t & 1;

    for (int kk = k0; kk < k1; kk += 32) {
        {   // stage A: tile [128 rows][32 k], LDS pitch 40 (bank-spread, 16B-aligned)
            const ushort* src = A + (size_t)(rowbase + srow) * lda + kk + shalf * 16;
            *(s16x8*)(sA + srow * 40 + shalf * 16)     = *(const s16x8*)(src);
            *(s16x8*)(sA + srow * 40 + shalf * 16 + 8) = *(const s16x8*)(src + 8);
        }
        if (!BT) {
            const ushort* src = B + (size_t)(colbase + srow) * ldb + kk + shalf * 16;
            *(s16x8*)(sB + srow * 40 + shalf * 16)     = *(const s16x8*)(src);
            *(s16x8*)(sB + srow * 40 + shalf * 16 + 8) = *(const s16x8*)(src + 8);
        } else {
            // transpose-stage: read B[k][col] 32B-contiguous, scatter into sB[col][k]
            const int kl = t & 31, d0c = (t >> 5) * 16;
            const ushort* src = B + (size_t)(kk + kl) * ldb + colbase + d0c;
            s16x8 v0 = *(const s16x8*)(src);
            s16x8 v1 = *(const s16x8*)(src + 8);
#pragma unroll
            for (int j = 0; j < 8; ++j) sB[(d0c + j) * 40 + kl]     = (ushort)v0[j];
#pragma unroll
            for (int j = 0; j < 8; ++j) sB[(d0c + 8 + j) * 40 + kl] = (ushort)v1[j];
        }
        __syncthreads();
        s16x8 a[4], b[4];
#pragma unroll
        for (int mi = 0; mi < 4; ++mi)
            a[mi] = *(const s16x8*)(sA + (wr + mi * 16 + fr) * 40 + fg * 8);
#pragma unroll
        for (int ni = 0; ni < 4; ++ni)
            b[ni] = *(const s16x8*)(sB + (wc + ni * 16 + fr) * 40 + fg * 8);
#pragma unroll
        for (int mi = 0; mi < 4; ++mi)
#pragma unroll
            for (int ni = 0; ni < 4; ++ni)
                acc[mi][ni] = __builtin_amdgcn_mfma_f32_16x16x32_bf16(
                    a[mi], b[ni], acc[mi][ni], 0, 0, 0);
        __syncthreads();
    }
}

// ---------- phi_kT: C[m, kl] = (Wt · style^T), epilogue exp -> phi_kT[b][m][kl] ----------
__global__ __launch_bounds__(256) void phikt_gemm(const ushort* __restrict__ Wt,
                                                  const ushort* __restrict__ Sb,
                                                  const float* __restrict__ sqk,
                                                  ushort* __restrict__ PhiKT) {
    __shared__ __align__(16) ushort sA[128 * 40];
    __shared__ __align__(16) ushort sB[128 * 40];
    f32x4 acc[4][4] = {};
    const int rowbase = blockIdx.y * 128;   // m
    const int colbase = blockIdx.x * 128;   // kl global (within one batch)
    gemm128<false>(Wt, DD, Sb, DD, rowbase, colbase, 0, DD, sA, sB, acc);

    const int t = threadIdx.x, l = t & 63, w = t >> 6;
    const int wr = (w >> 1) * 64, wc = (w & 1) * 64, fr = l & 15, fg = l >> 4;
    const int b = colbase >> 13;
    const int kll_base = colbase & (KLT - 1);
#pragma unroll
    for (int ni = 0; ni < 4; ++ni) {
        const int klg = colbase + wc + ni * 16 + fr;
        const int kll = kll_base + wc + ni * 16 + fr;
        const float sqv = sqk[klg];
#pragma unroll
        for (int mi = 0; mi < 4; ++mi)
#pragma unroll
            for (int rr = 0; rr < 4; ++rr) {
                const int m = rowbase + wr + mi * 16 + fg * 4 + rr;
                float v = __expf(acc[mi][ni][rr] * S1f - sqv) * S2f;
                PhiKT[((size_t)b << 21) + ((size_t)m << 13) + kll] = f2b(v);
            }
    }
}

// ---------- phi_q: C[l, m] = content · W, epilogue exp -> phi_q[l][m] ----------
__global__ __launch_bounds__(256) void phiq_gemm(const ushort* __restrict__ Cb,
                                                 const ushort* __restrict__ Wt,
                                                 const float* __restrict__ sqq,
                                                 ushort* __restrict__ PhiQ) {
    __shared__ __align__(16) ushort sA[128 * 40];
    __shared__ __align__(16) ushort sB[128 * 40];
    f32x4 acc[4][4] = {};
    const int rowbase = blockIdx.x * 128;   // l global
    const int colbase = blockIdx.y * 128;   // m
    gemm128<false>(Cb, DD, Wt, DD, rowbase, colbase, 0, DD, sA, sB, acc);

    const int t = threadIdx.x, l = t & 63, w = t >> 6;
    const int wr = (w >> 1) * 64, wc = (w & 1) * 64, fr = l & 15, fg = l >> 4;
#pragma unroll
    for (int mi = 0; mi < 4; ++mi)
#pragma unroll
        for (int rr = 0; rr < 4; ++rr) {
            const int lg = rowbase + wr + mi * 16 + fg * 4 + rr;
            const float sqv = sqq[lg];
#pragma unroll
            for (int ni = 0; ni < 4; ++ni) {
                const int m = colbase + wc + ni * 16 + fr;
                float v = __expf(acc[mi][ni][rr] * S1f - sqv) * S2f;
                PhiQ[(size_t)lg * MM + m] = f2b(v);
            }
        }
}

// ---------- S[b][m][d] += phi_kT[m][kl] * style[kl][d] ; split-K=4, fp32 atomics ----------
__global__ __launch_bounds__(256) void s_gemm(const ushort* __restrict__ PhiKT,
                                              const ushort* __restrict__ Sb,
                                              float* __restrict__ S) {
    __shared__ __align__(16) ushort sA[128 * 40];
    __shared__ __align__(16) ushort sB[128 * 40];
    f32x4 acc[4][4] = {};
    const int b = blockIdx.z >> 2, split = blockIdx.z & 3;
    const int rowbase = blockIdx.x * 128;   // m
    const int colbase = blockIdx.y * 128;   // d
    const ushort* A = PhiKT + ((size_t)b << 21);
    const ushort* B = Sb + (size_t)b * KLT * DD;
    gemm128<true>(A, KLT, B, DD, rowbase, colbase, split * 2048, split * 2048 + 2048,
                  sA, sB, acc);

    const int t = threadIdx.x, l = t & 63, w = t >> 6;
    const int wr = (w >> 1) * 64, wc = (w & 1) * 64, fr = l & 15, fg = l >> 4;
#pragma unroll
    for (int mi = 0; mi < 4; ++mi)
#pragma unroll
        for (int ni = 0; ni < 4; ++ni)
#pragma unroll
            for (int rr = 0; rr < 4; ++rr) {
                const int m = rowbase + wr + mi * 16 + fg * 4 + rr;
                const int d = colbase + wc + ni * 16 + fr;
                atomicAdd(&S[((size_t)b * MM + m) * DD + d], acc[mi][ni][rr]);
            }
}

// ---------- St[b][d][m] = bf16(S[b][m][d]) ; 64x64 LDS transpose ----------
__global__ __launch_bounds__(256) void s_fin(const float* __restrict__ S,
                                             ushort* __restrict__ St) {
    __shared__ ushort lds[64 * 78];
    const int t = threadIdx.x;
    const int mt = blockIdx.x, dt = blockIdx.y, b = blockIdx.z;
    {
        int r = t >> 2, c0 = (t & 3) * 16;   // r: m-local, c: d-local
        const float4* src =
            (const float4*)(S + ((size_t)b * MM + mt * 64 + r) * DD + dt * 64 + c0);
#pragma unroll
        for (int i = 0; i < 4; ++i) {
            float4 v = src[i];
            lds[r * 78 + c0 + 4 * i + 0] = f2b(v.x);
            lds[r * 78 + c0 + 4 * i + 1] = f2b(v.y);
            lds[r * 78 + c0 + 4 * i + 2] = f2b(v.z);
            lds[r * 78 + c0 + 4 * i + 3] = f2b(v.w);
        }
    }
    __syncthreads();
    {
        int d = t >> 2, m0 = (t & 3) * 16;
        ushort* dst = St + ((size_t)b * DD + dt * 64 + d) * MM + mt * 64 + m0;
#pragma unroll
        for (int j = 0; j < 16; ++j) dst[j] = lds[(m0 + j) * 78 + d];
    }
}

// ---------- Z[b][m] = sum_kl phi_kT[b][m][kl] ; one wave per row ----------
__global__ __launch_bounds__(256) void z_kernel(const ushort* __restrict__ PhiKT,
                                                float* __restrict__ Z) {
    const int row = blockIdx.x * 4 + (threadIdx.x >> 6);   // b*256 + m
    const int lane = threadIdx.x & 63;
    const int b = row >> 8, m = row & 255;
    const ushort* p = PhiKT + ((size_t)b << 21) + ((size_t)m << 13);
    float s = 0.f;
#pragma unroll
    for (int i = 0; i < 16; ++i) {
        s16x8 v = *(const s16x8*)(p + (size_t)(i * 64 + lane) * 8);
#pragma unroll
        for (int j = 0; j < 8; ++j) s += b2f((ushort)v[j]);
    }
#pragma unroll
    for (int off = 32; off; off >>= 1) s += __shfl_down(s, off);
    if (lane == 0) Z[row] = s;
}

// ---------- den[lg] = phi_q[lg,:] . Z[b,:] ; one wave per row ----------
__global__ __launch_bounds__(256) void den_kernel(const ushort* __restrict__ PhiQ,
                                                  const float* __restrict__ Z,
                                                  float* __restrict__ Den) {
    const int row = blockIdx.x * 4 + (threadIdx.x >> 6);
    const int lane = threadIdx.x & 63;
    const int b = row >> 11;
    typedef short s16x4 __attribute__((ext_vector_type(4)));
    s16x4 q = *(const s16x4*)(PhiQ + (size_t)row * MM + lane * 4);
    float4 z = *(const float4*)(Z + (size_t)b * MM + lane * 4);
    float s = b2f((ushort)q[0]) * z.x + b2f((ushort)q[1]) * z.y +
              b2f((ushort)q[2]) * z.z + b2f((ushort)q[3]) * z.w;
#pragma unroll
    for (int off = 32; off; off >>= 1) s += __shfl_down(s, off);
    if (lane == 0) Den[row] = s;
}

// ---------- out: num = phi_q · S ; f = num/(den+eps); amp = content + f ----------
__global__ __launch_bounds__(256) void out_gemm(const ushort* __restrict__ PhiQ,
                                                const ushort* __restrict__ St,
                                                const float* __restrict__ Den,
                                                const float* __restrict__ Content,
                                                float* __restrict__ Amp,
                                                float* __restrict__ Fa) {
    __shared__ __align__(16) ushort sA[128 * 40];
    __shared__ __align__(16) ushort sB[128 * 40];
    f32x4 acc[4][4] = {};
    const int b = blockIdx.z;
    const int rowbase = blockIdx.x * 128;   // l local
    const int colbase = blockIdx.y * 128;   // d
    const ushort* A = PhiQ + (size_t)b * LL * MM;
    const ushort* B = St + (size_t)b * DD * MM;
    gemm128<false>(A, MM, B, MM, rowbase, colbase, 0, MM, sA, sB, acc);

    const int t = threadIdx.x, l = t & 63, w = t >> 6;
    const int wr = (w >> 1) * 64, wc = (w & 1) * 64, fr = l & 15, fg = l >> 4;
#pragma unroll
    for (int mi = 0; mi < 4; ++mi)
#pragma unroll
        for (int rr = 0; rr < 4; ++rr) {
            const int lg = b * LL + rowbase + wr + mi * 16 + fg * 4 + rr;
            const float inv = 1.0f / (Den[lg] + EPSV);
#pragma unroll
            for (int ni = 0; ni < 4; ++ni) {
                const int d = colbase + wc + ni * 16 + fr;
                const size_t idx = (size_t)lg * DD + d;
                const float f = acc[mi][ni][rr] * inv;
                Fa[idx] = f;
                Amp[idx] = Content[idx] + f;
            }
        }
}

extern "C" void kernel_launch(void* const* d_in, const int* in_sizes, int n_in,
                              void* d_out, int out_size, void* d_ws, size_t ws_size,
                              hipStream_t stream) {
    const float* content = (const float*)d_in[0];   // [8,2048,512]
    const float* style   = (const float*)d_in[1];   // [8,4,2048,512] -> [65536,512]
    const float* Wm      = (const float*)d_in[2];   // [512,256]
    float* amp = (float*)d_out;
    float* fa  = (float*)d_out + (size_t)BB * LL * DD;

    // ---- workspace layout ----
    float* wsf   = (float*)d_ws;
    float* Sbuf  = wsf;                                   // 8*256*512       = 1,048,576 f
    float* sq_k  = Sbuf + (size_t)BB * MM * DD;           // 65,536 f
    float* sq_q  = sq_k + (size_t)BB * KLT;               // 16,384 f
    float* Zbuf  = sq_q + (size_t)BB * LL;                // 2,048 f
    float* den   = Zbuf + (size_t)BB * MM;                // 16,384 f
    ushort* wsu     = (ushort*)(den + (size_t)BB * LL);
    ushort* style_b = wsu;                                 // 65536*512  = 33,554,432 u
    ushort* cont_b  = style_b + (size_t)BB * KLT * DD;     // 16384*512  =  8,388,608 u
    ushort* Wt      = cont_b + (size_t)BB * LL * DD;       // 256*512    =    131,072 u
    ushort* phi_kT  = Wt + (size_t)MM * DD;                // 8*256*8192 = 16,777,216 u
    ushort* phi_q   = phi_kT + (size_t)BB * MM * KLT;      // 16384*256  =  4,194,304 u
    ushort* St      = phi_q + (size_t)BB * LL * MM;        // 8*512*256  =  1,048,576 u

    hipMemsetAsync(Sbuf, 0, (size_t)BB * MM * DD * sizeof(float), stream);

    prep_w<<<dim3(8, 4), 256, 0, stream>>>(Wm, Wt);
    convert_kernel<<<(BB * LL) / 64, 256, 0, stream>>>(content, cont_b, sq_q);
    convert_kernel<<<(BB * KLT) / 64, 256, 0, stream>>>(style, style_b, sq_k);

    phikt_gemm<<<dim3((BB * KLT) / 128, MM / 128), 256, 0, stream>>>(Wt, style_b, sq_k, phi_kT);
    phiq_gemm<<<dim3((BB * LL) / 128, MM / 128), 256, 0, stream>>>(cont_b, Wt, sq_q, phi_q);

    z_kernel<<<(BB * MM) / 4, 256, 0, stream>>>(phi_kT, Zbuf);
    s_gemm<<<dim3(MM / 128, DD / 128, BB * 4), 256, 0, stream>>>(phi_kT, style_b, Sbuf);
    s_fin<<<dim3(MM / 64, DD / 64, BB), 256, 0, stream>>>(Sbuf, St);

    den_kernel<<<(BB * LL) / 4, 256, 0, stream>>>(phi_q, Zbuf, den);
    out_gemm<<<dim3(LL / 128, DD / 128, BB), 256, 0, stream>>>(phi_q, St, den, content, amp, fa);
}

// Round 4
// 443.565 us; speedup vs baseline: 1.8736x; 1.0495x over previous
//
#include <hip/hip_runtime.h>
#include <hip/hip_bf16.h>
#include <math.h>

typedef short  s16x8 __attribute__((ext_vector_type(8)));
typedef short  s16x4 __attribute__((ext_vector_type(4)));
typedef float  f32x4 __attribute__((ext_vector_type(4)));

#define DD 512      // feature dim d
#define MM 256      // random features m
#define BB 8
#define LL 2048
#define KLT 8192    // K*L style rows per batch

#define S1f     0.21022410381342864f   // 512^-0.25
#define INV2SDf 0.02209708691207961f   // 1/(2*sqrt(512))
#define S2f     0.0625f                // 256^-0.5
#define EPSV    1e-8f

__device__ __forceinline__ ushort f2b(float f) {
    __hip_bfloat16 h = __float2bfloat16(f);
    return *reinterpret_cast<ushort*>(&h);
}
__device__ __forceinline__ float b2f(ushort u) {
    union { unsigned u32; float f; } x; x.u32 = ((unsigned)u) << 16; return x.f;
}

// ---------- coalesced fp32 -> bf16 convert + per-row sq ----------
// One wave per row (512 floats): lane reads float4[lane], float4[lane+64].
__global__ __launch_bounds__(256) void convert_rows(const float* __restrict__ X,
                                                    ushort* __restrict__ Xb,
                                                    float* __restrict__ Sq) {
    const int row  = blockIdx.x * 4 + (threadIdx.x >> 6);
    const int lane = threadIdx.x & 63;
    const float4* src = (const float4*)(X + (size_t)row * DD);
    float4 v0 = src[lane];
    float4 v1 = src[lane + 64];
    float s = v0.x * v0.x + v0.y * v0.y + v0.z * v0.z + v0.w * v0.w
            + v1.x * v1.x + v1.y * v1.y + v1.z * v1.z + v1.w * v1.w;
    s16x4* dst = (s16x4*)(Xb + (size_t)row * DD);
    s16x4 o0, o1;
    o0[0] = (short)f2b(v0.x); o0[1] = (short)f2b(v0.y);
    o0[2] = (short)f2b(v0.z); o0[3] = (short)f2b(v0.w);
    o1[0] = (short)f2b(v1.x); o1[1] = (short)f2b(v1.y);
    o1[2] = (short)f2b(v1.z); o1[3] = (short)f2b(v1.w);
    dst[lane]      = o0;
    dst[lane + 64] = o1;
#pragma unroll
    for (int off = 32; off; off >>= 1) s += __shfl_down(s, off);
    if (lane == 0) Sq[row] = s * INV2SDf;
}

// ---------- Wt[m][d] = bf16(W[d][m]) ; 64x64 LDS tile transpose ----------
__global__ __launch_bounds__(256) void prep_w(const float* __restrict__ W,
                                              ushort* __restrict__ Wt) {
    __shared__ ushort lds[64 * 78];
    const int t = threadIdx.x;
    const int dt = blockIdx.x;   // 0..7
    const int mt = blockIdx.y;   // 0..3
    {
        int r = t >> 2, c0 = (t & 3) * 16;   // r: d-local, c: m-local
        const float4* src = (const float4*)(W + (size_t)(dt * 64 + r) * MM + mt * 64 + c0);
#pragma unroll
        for (int i = 0; i < 4; ++i) {
            float4 v = src[i];
            lds[r * 78 + c0 + 4 * i + 0] = f2b(v.x);
            lds[r * 78 + c0 + 4 * i + 1] = f2b(v.y);
            lds[r * 78 + c0 + 4 * i + 2] = f2b(v.z);
            lds[r * 78 + c0 + 4 * i + 3] = f2b(v.w);
        }
    }
    __syncthreads();
    {
        int m = t >> 2, d0 = (t & 3) * 16;
        ushort* dst = Wt + (size_t)(mt * 64 + m) * DD + dt * 64 + d0;
#pragma unroll
        for (int j = 0; j < 16; ++j) dst[j] = lds[(d0 + j) * 78 + m];
    }
}

// ---------- styleT[b][d][kl] = style_b[b][kl][d] ; bf16 64x64 tile transpose ----------
__global__ __launch_bounds__(256) void transpose_k(const ushort* __restrict__ Sb,
                                                   ushort* __restrict__ StyT) {
    __shared__ ushort lds[64 * 72];
    const int t = threadIdx.x;
    const int klt = blockIdx.x;   // 0..127
    const int dt  = blockIdx.y;   // 0..7
    const int b   = blockIdx.z;
    {
        int r = t >> 2, c0 = (t & 3) * 16;   // r: kl-local, c: d-local
        const ushort* src = Sb + ((size_t)b * KLT + klt * 64 + r) * DD + dt * 64 + c0;
        *(s16x8*)(lds + r * 72 + c0)     = *(const s16x8*)(src);
        *(s16x8*)(lds + r * 72 + c0 + 8) = *(const s16x8*)(src + 8);
    }
    __syncthreads();
    {
        int d = t >> 2, k0 = (t & 3) * 16;
        s16x8 o0, o1;
#pragma unroll
        for (int j = 0; j < 8; ++j) o0[j] = (short)lds[(k0 + j) * 72 + d];
#pragma unroll
        for (int j = 0; j < 8; ++j) o1[j] = (short)lds[(k0 + 8 + j) * 72 + d];
        ushort* dst = StyT + ((size_t)b * DD + dt * 64 + d) * KLT + klt * 64 + k0;
        *(s16x8*)(dst)     = o0;
        *(s16x8*)(dst + 8) = o1;
    }
}

// ---------- unified 128x128 BK=32 bf16 MFMA core (both operands k-contiguous) ----------
__device__ __forceinline__ void gemm128(const ushort* __restrict__ A, int lda,
                                        const ushort* __restrict__ B, int ldb,
                                        int rowbase, int colbase, int k0, int k1,
                                        ushort* sA, ushort* sB, f32x4 acc[4][4]) {
    const int t = threadIdx.x;
    const int l = t & 63, w = t >> 6;
    const int wr = (w >> 1) * 64, wc = (w & 1) * 64;
    const int fr = l & 15, fg = l >> 4;
    const int srow = t >> 1, shalf = t & 1;

    for (int kk = k0; kk < k1; kk += 32) {
        {
            const ushort* src = A + (size_t)(rowbase + srow) * lda + kk + shalf * 16;
            *(s16x8*)(sA + srow * 40 + shalf * 16)     = *(const s16x8*)(src);
            *(s16x8*)(sA + srow * 40 + shalf * 16 + 8) = *(const s16x8*)(src + 8);
        }
        {
            const ushort* src = B + (size_t)(colbase + srow) * ldb + kk + shalf * 16;
            *(s16x8*)(sB + srow * 40 + shalf * 16)     = *(const s16x8*)(src);
            *(s16x8*)(sB + srow * 40 + shalf * 16 + 8) = *(const s16x8*)(src + 8);
        }
        __syncthreads();
        s16x8 a[4], b[4];
#pragma unroll
        for (int mi = 0; mi < 4; ++mi)
            a[mi] = *(const s16x8*)(sA + (wr + mi * 16 + fr) * 40 + fg * 8);
#pragma unroll
        for (int ni = 0; ni < 4; ++ni)
            b[ni] = *(const s16x8*)(sB + (wc + ni * 16 + fr) * 40 + fg * 8);
#pragma unroll
        for (int mi = 0; mi < 4; ++mi)
#pragma unroll
            for (int ni = 0; ni < 4; ++ni)
                acc[mi][ni] = __builtin_amdgcn_mfma_f32_16x16x32_bf16(
                    a[mi], b[ni], acc[mi][ni], 0, 0, 0);
        __syncthreads();
    }
}

// ---------- phi_kT: C[m, kl] = (Wt · style^T), epilogue exp -> phi_kT[b][m][kl] ----------
__global__ __launch_bounds__(256) void phikt_gemm(const ushort* __restrict__ Wt,
                                                  const ushort* __restrict__ Sb,
                                                  const float* __restrict__ sqk,
                                                  ushort* __restrict__ PhiKT) {
    __shared__ __align__(16) ushort sA[128 * 40];
    __shared__ __align__(16) ushort sB[128 * 40];
    f32x4 acc[4][4] = {};
    const int rowbase = blockIdx.y * 128;   // m
    const int colbase = blockIdx.x * 128;   // kl global
    gemm128(Wt, DD, Sb, DD, rowbase, colbase, 0, DD, sA, sB, acc);

    const int t = threadIdx.x, l = t & 63, w = t >> 6;
    const int wr = (w >> 1) * 64, wc = (w & 1) * 64, fr = l & 15, fg = l >> 4;
    const int b = colbase >> 13;
    const int kll_base = colbase & (KLT - 1);
#pragma unroll
    for (int ni = 0; ni < 4; ++ni) {
        const int klg = colbase + wc + ni * 16 + fr;
        const int kll = kll_base + wc + ni * 16 + fr;
        const float sqv = sqk[klg];
#pragma unroll
        for (int mi = 0; mi < 4; ++mi)
#pragma unroll
            for (int rr = 0; rr < 4; ++rr) {
                const int m = rowbase + wr + mi * 16 + fg * 4 + rr;
                float v = __expf(acc[mi][ni][rr] * S1f - sqv) * S2f;
                PhiKT[((size_t)b << 21) + ((size_t)m << 13) + kll] = f2b(v);
            }
    }
}

// ---------- phi_q: C[l, m] = content · W, epilogue exp -> phi_q[l][m] ----------
__global__ __launch_bounds__(256) void phiq_gemm(const ushort* __restrict__ Cb,
                                                 const ushort* __restrict__ Wt,
                                                 const float* __restrict__ sqq,
                                                 ushort* __restrict__ PhiQ) {
    __shared__ __align__(16) ushort sA[128 * 40];
    __shared__ __align__(16) ushort sB[128 * 40];
    f32x4 acc[4][4] = {};
    const int rowbase = blockIdx.x * 128;   // l global
    const int colbase = blockIdx.y * 128;   // m
    gemm128(Cb, DD, Wt, DD, rowbase, colbase, 0, DD, sA, sB, acc);

    const int t = threadIdx.x, l = t & 63, w = t >> 6;
    const int wr = (w >> 1) * 64, wc = (w & 1) * 64, fr = l & 15, fg = l >> 4;
#pragma unroll
    for (int mi = 0; mi < 4; ++mi)
#pragma unroll
        for (int rr = 0; rr < 4; ++rr) {
            const int lg = rowbase + wr + mi * 16 + fg * 4 + rr;
            const float sqv = sqq[lg];
#pragma unroll
            for (int ni = 0; ni < 4; ++ni) {
                const int m = colbase + wc + ni * 16 + fr;
                float v = __expf(acc[mi][ni][rr] * S1f - sqv) * S2f;
                PhiQ[(size_t)lg * MM + m] = f2b(v);
            }
        }
}

// ---------- S[b][m][d] += phi_kT[m][kl] * styleT[d][kl] ; split-K=8, fp32 atomics ----------
__global__ __launch_bounds__(256) void s_gemm(const ushort* __restrict__ PhiKT,
                                              const ushort* __restrict__ StyT,
                                              float* __restrict__ S) {
    __shared__ __align__(16) ushort sA[128 * 40];
    __shared__ __align__(16) ushort sB[128 * 40];
    f32x4 acc[4][4] = {};
    const int b = blockIdx.z >> 3, split = blockIdx.z & 7;
    const int rowbase = blockIdx.x * 128;   // m
    const int colbase = blockIdx.y * 128;   // d
    const ushort* A = PhiKT + ((size_t)b << 21);
    const ushort* B = StyT + (size_t)b * DD * KLT;
    gemm128(A, KLT, B, KLT, rowbase, colbase, split * 1024, split * 1024 + 1024,
            sA, sB, acc);

    const int t = threadIdx.x, l = t & 63, w = t >> 6;
    const int wr = (w >> 1) * 64, wc = (w & 1) * 64, fr = l & 15, fg = l >> 4;
#pragma unroll
    for (int mi = 0; mi < 4; ++mi)
#pragma unroll
        for (int ni = 0; ni < 4; ++ni)
#pragma unroll
            for (int rr = 0; rr < 4; ++rr) {
                const int m = rowbase + wr + mi * 16 + fg * 4 + rr;
                const int d = colbase + wc + ni * 16 + fr;
                atomicAdd(&S[((size_t)b * MM + m) * DD + d], acc[mi][ni][rr]);
            }
}

// ---------- St[b][d][m] = bf16(S[b][m][d]) ; 64x64 LDS transpose ----------
__global__ __launch_bounds__(256) void s_fin(const float* __restrict__ S,
                                             ushort* __restrict__ St) {
    __shared__ ushort lds[64 * 78];
    const int t = threadIdx.x;
    const int mt = blockIdx.x, dt = blockIdx.y, b = blockIdx.z;
    {
        int r = t >> 2, c0 = (t & 3) * 16;   // r: m-local, c: d-local
        const float4* src =
            (const float4*)(S + ((size_t)b * MM + mt * 64 + r) * DD + dt * 64 + c0);
#pragma unroll
        for (int i = 0; i < 4; ++i) {
            float4 v = src[i];
            lds[r * 78 + c0 + 4 * i + 0] = f2b(v.x);
            lds[r * 78 + c0 + 4 * i + 1] = f2b(v.y);
            lds[r * 78 + c0 + 4 * i + 2] = f2b(v.z);
            lds[r * 78 + c0 + 4 * i + 3] = f2b(v.w);
        }
    }
    __syncthreads();
    {
        int d = t >> 2, m0 = (t & 3) * 16;
        ushort* dst = St + ((size_t)b * DD + dt * 64 + d) * MM + mt * 64 + m0;
#pragma unroll
        for (int j = 0; j < 16; ++j) dst[j] = lds[(m0 + j) * 78 + d];
    }
}

// ---------- Z[b][m] = sum_kl phi_kT[b][m][kl] ; one wave per row ----------
__global__ __launch_bounds__(256) void z_kernel(const ushort* __restrict__ PhiKT,
                                                float* __restrict__ Z) {
    const int row = blockIdx.x * 4 + (threadIdx.x >> 6);   // b*256 + m
    const int lane = threadIdx.x & 63;
    const int b = row >> 8, m = row & 255;
    const ushort* p = PhiKT + ((size_t)b << 21) + ((size_t)m << 13);
    float s = 0.f;
#pragma unroll
    for (int i = 0; i < 16; ++i) {
        s16x8 v = *(const s16x8*)(p + (size_t)(i * 64 + lane) * 8);
#pragma unroll
        for (int j = 0; j < 8; ++j) s += b2f((ushort)v[j]);
    }
#pragma unroll
    for (int off = 32; off; off >>= 1) s += __shfl_down(s, off);
    if (lane == 0) Z[row] = s;
}

// ---------- den[lg] = phi_q[lg,:] . Z[b,:] ; one wave per row ----------
__global__ __launch_bounds__(256) void den_kernel(const ushort* __restrict__ PhiQ,
                                                  const float* __restrict__ Z,
                                                  float* __restrict__ Den) {
    const int row = blockIdx.x * 4 + (threadIdx.x >> 6);
    const int lane = threadIdx.x & 63;
    const int b = row >> 11;
    s16x4 q = *(const s16x4*)(PhiQ + (size_t)row * MM + lane * 4);
    float4 z = *(const float4*)(Z + (size_t)b * MM + lane * 4);
    float s = b2f((ushort)q[0]) * z.x + b2f((ushort)q[1]) * z.y +
              b2f((ushort)q[2]) * z.z + b2f((ushort)q[3]) * z.w;
#pragma unroll
    for (int off = 32; off; off >>= 1) s += __shfl_down(s, off);
    if (lane == 0) Den[row] = s;
}

// ---------- out: num = phi_q · S ; f = num/(den+eps); amp = content + f ----------
__global__ __launch_bounds__(256) void out_gemm(const ushort* __restrict__ PhiQ,
                                                const ushort* __restrict__ St,
                                                const float* __restrict__ Den,
                                                const float* __restrict__ Content,
                                                float* __restrict__ Amp,
                                                float* __restrict__ Fa) {
    __shared__ __align__(16) ushort sA[128 * 40];
    __shared__ __align__(16) ushort sB[128 * 40];
    f32x4 acc[4][4] = {};
    const int b = blockIdx.z;
    const int rowbase = blockIdx.x * 128;   // l local
    const int colbase = blockIdx.y * 128;   // d
    const ushort* A = PhiQ + (size_t)b * LL * MM;
    const ushort* B = St + (size_t)b * DD * MM;
    gemm128(A, MM, B, MM, rowbase, colbase, 0, MM, sA, sB, acc);

    const int t = threadIdx.x, l = t & 63, w = t >> 6;
    const int wr = (w >> 1) * 64, wc = (w & 1) * 64, fr = l & 15, fg = l >> 4;
#pragma unroll
    for (int mi = 0; mi < 4; ++mi)
#pragma unroll
        for (int rr = 0; rr < 4; ++rr) {
            const int lg = b * LL + rowbase + wr + mi * 16 + fg * 4 + rr;
            const float inv = 1.0f / (Den[lg] + EPSV);
#pragma unroll
            for (int ni = 0; ni < 4; ++ni) {
                const int d = colbase + wc + ni * 16 + fr;
                const size_t idx = (size_t)lg * DD + d;
                const float f = acc[mi][ni][rr] * inv;
                Fa[idx] = f;
                Amp[idx] = Content[idx] + f;
            }
        }
}

extern "C" void kernel_launch(void* const* d_in, const int* in_sizes, int n_in,
                              void* d_out, int out_size, void* d_ws, size_t ws_size,
                              hipStream_t stream) {
    const float* content = (const float*)d_in[0];   // [8,2048,512]
    const float* style   = (const float*)d_in[1];   // [8,4,2048,512] -> [65536,512]
    const float* Wm      = (const float*)d_in[2];   // [512,256]
    float* amp = (float*)d_out;
    float* fa  = (float*)d_out + (size_t)BB * LL * DD;

    // styleT (bf16, [b][d][kl], 67 MB) lives in d_out: it is scratch until
    // out_gemm overwrites d_out at the very end. Sizes match exactly:
    // 8*512*8192*2B == 2*8*2048*512*4B.
    ushort* styleT = (ushort*)d_out;

    // ---- workspace layout ----
    float* wsf   = (float*)d_ws;
    float* Sbuf  = wsf;                                   // 1,048,576 f
    float* sq_k  = Sbuf + (size_t)BB * MM * DD;           // 65,536 f
    float* sq_q  = sq_k + (size_t)BB * KLT;               // 16,384 f
    float* Zbuf  = sq_q + (size_t)BB * LL;                // 2,048 f
    float* den   = Zbuf + (size_t)BB * MM;                // 16,384 f
    ushort* wsu     = (ushort*)(den + (size_t)BB * LL);
    ushort* style_b = wsu;                                 // 33,554,432 u
    ushort* cont_b  = style_b + (size_t)BB * KLT * DD;     //  8,388,608 u
    ushort* Wt      = cont_b + (size_t)BB * LL * DD;       //    131,072 u
    ushort* phi_kT  = Wt + (size_t)MM * DD;                // 16,777,216 u
    ushort* phi_q   = phi_kT + (size_t)BB * MM * KLT;      //  4,194,304 u
    ushort* St      = phi_q + (size_t)BB * LL * MM;        //  1,048,576 u

    hipMemsetAsync(Sbuf, 0, (size_t)BB * MM * DD * sizeof(float), stream);

    prep_w<<<dim3(8, 4), 256, 0, stream>>>(Wm, Wt);
    convert_rows<<<(BB * LL) / 4, 256, 0, stream>>>(content, cont_b, sq_q);
    convert_rows<<<(BB * KLT) / 4, 256, 0, stream>>>(style, style_b, sq_k);

    phikt_gemm<<<dim3((BB * KLT) / 128, MM / 128), 256, 0, stream>>>(Wt, style_b, sq_k, phi_kT);
    phiq_gemm<<<dim3((BB * LL) / 128, MM / 128), 256, 0, stream>>>(cont_b, Wt, sq_q, phi_q);

    transpose_k<<<dim3(KLT / 64, DD / 64, BB), 256, 0, stream>>>(style_b, styleT);

    z_kernel<<<(BB * MM) / 4, 256, 0, stream>>>(phi_kT, Zbuf);
    s_gemm<<<dim3(MM / 128, DD / 128, BB * 8), 256, 0, stream>>>(phi_kT, styleT, Sbuf);
    s_fin<<<dim3(MM / 64, DD / 64, BB), 256, 0, stream>>>(Sbuf, St);

    den_kernel<<<(BB * LL) / 4, 256, 0, stream>>>(phi_q, Zbuf, den);
    out_gemm<<<dim3(LL / 128, DD / 128, BB), 256, 0, stream>>>(phi_q, St, den, content, amp, fa);
}

// Round 5
// 418.960 us; speedup vs baseline: 1.9837x; 1.0587x over previous
//
#include <hip/hip_runtime.h>
#include <hip/hip_bf16.h>
#include <math.h>

typedef short  s16x8 __attribute__((ext_vector_type(8)));
typedef short  s16x4 __attribute__((ext_vector_type(4)));
typedef float  f32x4 __attribute__((ext_vector_type(4)));

#define DD 512      // feature dim d
#define MM 256      // random features m
#define BB 8
#define LL 2048
#define KLT 8192    // K*L style rows per batch
#define NSPLIT 8    // split-K for s_gemm

#define S1f     0.21022410381342864f   // 512^-0.25
#define INV2SDf 0.02209708691207961f   // 1/(2*sqrt(512))
#define S2f     0.0625f                // 256^-0.5
#define EPSV    1e-8f

__device__ __forceinline__ ushort f2b(float f) {
    __hip_bfloat16 h = __float2bfloat16(f);
    return *reinterpret_cast<ushort*>(&h);
}
__device__ __forceinline__ float b2f(ushort u) {
    union { unsigned u32; float f; } x; x.u32 = ((unsigned)u) << 16; return x.f;
}

// async global->LDS, 16 B per lane, linear dest (wave-uniform base + lane*16)
__device__ __forceinline__ void gl_lds16(const ushort* g, ushort* l) {
    __builtin_amdgcn_global_load_lds(
        (const __attribute__((address_space(1))) unsigned int*)(const void*)g,
        (__attribute__((address_space(3))) unsigned int*)(void*)l,
        16, 0, 0);
}

// ---------- coalesced fp32 -> bf16 convert + per-row sq (content) ----------
__global__ __launch_bounds__(256) void convert_rows(const float* __restrict__ X,
                                                    ushort* __restrict__ Xb,
                                                    float* __restrict__ Sq) {
    const int row  = blockIdx.x * 4 + (threadIdx.x >> 6);
    const int lane = threadIdx.x & 63;
    const float4* src = (const float4*)(X + (size_t)row * DD);
    float4 v0 = src[lane];
    float4 v1 = src[lane + 64];
    float s = v0.x * v0.x + v0.y * v0.y + v0.z * v0.z + v0.w * v0.w
            + v1.x * v1.x + v1.y * v1.y + v1.z * v1.z + v1.w * v1.w;
    s16x4* dst = (s16x4*)(Xb + (size_t)row * DD);
    s16x4 o0, o1;
    o0[0] = (short)f2b(v0.x); o0[1] = (short)f2b(v0.y);
    o0[2] = (short)f2b(v0.z); o0[3] = (short)f2b(v0.w);
    o1[0] = (short)f2b(v1.x); o1[1] = (short)f2b(v1.y);
    o1[2] = (short)f2b(v1.z); o1[3] = (short)f2b(v1.w);
    dst[lane]      = o0;
    dst[lane + 64] = o1;
#pragma unroll
    for (int off = 32; off; off >>= 1) s += __shfl_down(s, off);
    if (lane == 0) Sq[row] = s * INV2SDf;
}

// ---------- fused style: fp32 -> bf16 [kl][d], bf16 [d][kl], sq partials ----------
// 64x64 tiles. grid (KLT/64, DD/64, BB)
__global__ __launch_bounds__(256) void conv_style(const float* __restrict__ X,
                                                  ushort* __restrict__ Xb,
                                                  ushort* __restrict__ XT,
                                                  float* __restrict__ Sq) {
    __shared__ ushort lds[64 * 72];
    const int t = threadIdx.x;
    const int klt = blockIdx.x, dt = blockIdx.y, b = blockIdx.z;
    const int r = t >> 2, c0 = (t & 3) * 16;
    const size_t rowg = (size_t)b * KLT + klt * 64 + r;
    const float4* src = (const float4*)(X + rowg * DD + dt * 64 + c0);
    float s = 0.f;
    s16x8 o0, o1;
#pragma unroll
    for (int i = 0; i < 2; ++i) {
        float4 v = src[2 * i], w = src[2 * i + 1];
        s += v.x * v.x + v.y * v.y + v.z * v.z + v.w * v.w
           + w.x * w.x + w.y * w.y + w.z * w.z + w.w * w.w;
        s16x8 o;
        o[0] = (short)f2b(v.x); o[1] = (short)f2b(v.y);
        o[2] = (short)f2b(v.z); o[3] = (short)f2b(v.w);
        o[4] = (short)f2b(w.x); o[5] = (short)f2b(w.y);
        o[6] = (short)f2b(w.z); o[7] = (short)f2b(w.w);
        if (i == 0) o0 = o; else o1 = o;
    }
    // natural-layout bf16 write
    ushort* dstb = Xb + rowg * DD + dt * 64 + c0;
    *(s16x8*)(dstb)     = o0;
    *(s16x8*)(dstb + 8) = o1;
    // stash for transpose
    *(s16x8*)(lds + r * 72 + c0)     = o0;
    *(s16x8*)(lds + r * 72 + c0 + 8) = o1;
    // sq partial: 4 threads per row -> 1 atomic
    s += __shfl_xor(s, 1);
    s += __shfl_xor(s, 2);
    if ((t & 3) == 0) atomicAdd(&Sq[rowg], s * INV2SDf);
    __syncthreads();
    // transposed write [d][kl]
    const int d = t >> 2, k0c = (t & 3) * 16;
    s16x8 t0, t1;
#pragma unroll
    for (int j = 0; j < 8; ++j) t0[j] = (short)lds[(k0c + j) * 72 + d];
#pragma unroll
    for (int j = 0; j < 8; ++j) t1[j] = (short)lds[(k0c + 8 + j) * 72 + d];
    ushort* dstT = XT + ((size_t)b * DD + dt * 64 + d) * KLT + klt * 64 + k0c;
    *(s16x8*)(dstT)     = t0;
    *(s16x8*)(dstT + 8) = t1;
}

// ---------- Wt[m][d] = bf16(W[d][m]) ; 64x64 LDS tile transpose ----------
__global__ __launch_bounds__(256) void prep_w(const float* __restrict__ W,
                                              ushort* __restrict__ Wt) {
    __shared__ ushort lds[64 * 78];
    const int t = threadIdx.x;
    const int dt = blockIdx.x;   // 0..7
    const int mt = blockIdx.y;   // 0..3
    {
        int r = t >> 2, c0 = (t & 3) * 16;   // r: d-local, c: m-local
        const float4* src = (const float4*)(W + (size_t)(dt * 64 + r) * MM + mt * 64 + c0);
#pragma unroll
        for (int i = 0; i < 4; ++i) {
            float4 v = src[i];
            lds[r * 78 + c0 + 4 * i + 0] = f2b(v.x);
            lds[r * 78 + c0 + 4 * i + 1] = f2b(v.y);
            lds[r * 78 + c0 + 4 * i + 2] = f2b(v.z);
            lds[r * 78 + c0 + 4 * i + 3] = f2b(v.w);
        }
    }
    __syncthreads();
    {
        int m = t >> 2, d0 = (t & 3) * 16;
        ushort* dst = Wt + (size_t)(mt * 64 + m) * DD + dt * 64 + d0;
#pragma unroll
        for (int j = 0; j < 16; ++j) dst[j] = lds[(d0 + j) * 78 + m];
    }
}

// ---------- 128x128 BK=32 bf16 MFMA core, global_load_lds staging ----------
// A: [rows][K] (lda), B: [cols][K] (ldb), both k-contiguous bf16.
// LDS tiles linear [128][32] (64 B rows) as required by global_load_lds.
__device__ __forceinline__ void gemm128(const ushort* __restrict__ A, int lda,
                                        const ushort* __restrict__ B, int ldb,
                                        int rowbase, int colbase, int k0, int k1,
                                        ushort* sA, ushort* sB, f32x4 acc[4][4]) {
    const int t = threadIdx.x;
    const int l = t & 63, w = t >> 6;
    const int wr = (w >> 1) * 64, wc = (w & 1) * 64;
    const int fr = l & 15, fg = l >> 4;
    const int lrow = l >> 2, lk = (l & 3) * 8;   // lane's row-in-group / k-chunk

    for (int kk = k0; kk < k1; kk += 32) {
        // each wave stages 2 groups of 16 rows for A and for B
        gl_lds16(A + (size_t)(rowbase + w * 16 + lrow) * lda + kk + lk,
                 sA + (w * 16) * 32);
        gl_lds16(A + (size_t)(rowbase + (w + 4) * 16 + lrow) * lda + kk + lk,
                 sA + ((w + 4) * 16) * 32);
        gl_lds16(B + (size_t)(colbase + w * 16 + lrow) * ldb + kk + lk,
                 sB + (w * 16) * 32);
        gl_lds16(B + (size_t)(colbase + (w + 4) * 16 + lrow) * ldb + kk + lk,
                 sB + ((w + 4) * 16) * 32);
        __syncthreads();   // compiler drains vmcnt before barrier
        s16x8 a[4], b[4];
#pragma unroll
        for (int mi = 0; mi < 4; ++mi)
            a[mi] = *(const s16x8*)(sA + (wr + mi * 16 + fr) * 32 + fg * 8);
#pragma unroll
        for (int ni = 0; ni < 4; ++ni)
            b[ni] = *(const s16x8*)(sB + (wc + ni * 16 + fr) * 32 + fg * 8);
#pragma unroll
        for (int mi = 0; mi < 4; ++mi)
#pragma unroll
            for (int ni = 0; ni < 4; ++ni)
                acc[mi][ni] = __builtin_amdgcn_mfma_f32_16x16x32_bf16(
                    a[mi], b[ni], acc[mi][ni], 0, 0, 0);
        __syncthreads();
    }
}

// ---------- phi_kT: C[m, kl] = Wt · style^T, exp epilogue -> phi_kT[b][m][kl] ----------
__global__ __launch_bounds__(256) void phikt_gemm(const ushort* __restrict__ Wt,
                                                  const ushort* __restrict__ Sb,
                                                  const float* __restrict__ sqk,
                                                  ushort* __restrict__ PhiKT) {
    __shared__ __align__(16) ushort sA[128 * 32];
    __shared__ __align__(16) ushort sB[128 * 32];
    f32x4 acc[4][4] = {};
    const int rowbase = blockIdx.y * 128;   // m
    const int colbase = blockIdx.x * 128;   // kl global
    gemm128(Wt, DD, Sb, DD, rowbase, colbase, 0, DD, sA, sB, acc);

    const int t = threadIdx.x, l = t & 63, w = t >> 6;
    const int wr = (w >> 1) * 64, wc = (w & 1) * 64, fr = l & 15, fg = l >> 4;
    const int b = colbase >> 13;
    const int kll_base = colbase & (KLT - 1);
#pragma unroll
    for (int ni = 0; ni < 4; ++ni) {
        const int klg = colbase + wc + ni * 16 + fr;
        const int kll = kll_base + wc + ni * 16 + fr;
        const float sqv = sqk[klg];
#pragma unroll
        for (int mi = 0; mi < 4; ++mi)
#pragma unroll
            for (int rr = 0; rr < 4; ++rr) {
                const int m = rowbase + wr + mi * 16 + fg * 4 + rr;
                float v = __expf(acc[mi][ni][rr] * S1f - sqv) * S2f;
                PhiKT[((size_t)b << 21) + ((size_t)m << 13) + kll] = f2b(v);
            }
    }
}

// ---------- phi_q: C[l, m] = content · W, exp epilogue -> phi_q[l][m] ----------
__global__ __launch_bounds__(256) void phiq_gemm(const ushort* __restrict__ Cb,
                                                 const ushort* __restrict__ Wt,
                                                 const float* __restrict__ sqq,
                                                 ushort* __restrict__ PhiQ) {
    __shared__ __align__(16) ushort sA[128 * 32];
    __shared__ __align__(16) ushort sB[128 * 32];
    f32x4 acc[4][4] = {};
    const int rowbase = blockIdx.x * 128;   // l global
    const int colbase = blockIdx.y * 128;   // m
    gemm128(Cb, DD, Wt, DD, rowbase, colbase, 0, DD, sA, sB, acc);

    const int t = threadIdx.x, l = t & 63, w = t >> 6;
    const int wr = (w >> 1) * 64, wc = (w & 1) * 64, fr = l & 15, fg = l >> 4;
#pragma unroll
    for (int mi = 0; mi < 4; ++mi)
#pragma unroll
        for (int rr = 0; rr < 4; ++rr) {
            const int lg = rowbase + wr + mi * 16 + fg * 4 + rr;
            const float sqv = sqq[lg];
#pragma unroll
            for (int ni = 0; ni < 4; ++ni) {
                const int m = colbase + wc + ni * 16 + fr;
                float v = __expf(acc[mi][ni][rr] * S1f - sqv) * S2f;
                PhiQ[(size_t)lg * MM + m] = f2b(v);
            }
        }
}

// ---------- S partials: Spart[split][b][m][d] = phi_kT slice · styleT slice ----------
__global__ __launch_bounds__(256) void s_gemm(const ushort* __restrict__ PhiKT,
                                              const ushort* __restrict__ StyT,
                                              float* __restrict__ Spart) {
    __shared__ __align__(16) ushort sA[128 * 32];
    __shared__ __align__(16) ushort sB[128 * 32];
    f32x4 acc[4][4] = {};
    const int b = blockIdx.z >> 3, split = blockIdx.z & 7;
    const int rowbase = blockIdx.x * 128;   // m
    const int colbase = blockIdx.y * 128;   // d
    const ushort* A = PhiKT + ((size_t)b << 21);
    const ushort* B = StyT + (size_t)b * DD * KLT;
    gemm128(A, KLT, B, KLT, rowbase, colbase, split * 1024, split * 1024 + 1024,
            sA, sB, acc);

    const int t = threadIdx.x, l = t & 63, w = t >> 6;
    const int wr = (w >> 1) * 64, wc = (w & 1) * 64, fr = l & 15, fg = l >> 4;
    float* out = Spart + (size_t)(split * BB + b) * MM * DD;
#pragma unroll
    for (int mi = 0; mi < 4; ++mi)
#pragma unroll
        for (int ni = 0; ni < 4; ++ni)
#pragma unroll
            for (int rr = 0; rr < 4; ++rr) {
                const int m = rowbase + wr + mi * 16 + fg * 4 + rr;
                const int d = colbase + wc + ni * 16 + fr;
                out[(size_t)m * DD + d] = acc[mi][ni][rr];
            }
}

// ---------- St[b][d][m] = bf16(sum_split Spart) ; reduce + 64x64 transpose ----------
__global__ __launch_bounds__(256) void s_fin(const float* __restrict__ Sp,
                                             ushort* __restrict__ St) {
    __shared__ ushort lds[64 * 78];
    const int t = threadIdx.x;
    const int mt = blockIdx.x, dt = blockIdx.y, b = blockIdx.z;
    {
        const int r = t >> 2, c0 = (t & 3) * 16;   // r: m-local, c: d-local
        float accv[16];
#pragma unroll
        for (int j = 0; j < 16; ++j) accv[j] = 0.f;
#pragma unroll
        for (int sp = 0; sp < NSPLIT; ++sp) {
            const float4* src = (const float4*)(Sp +
                ((size_t)(sp * BB + b) * MM + mt * 64 + r) * DD + dt * 64 + c0);
#pragma unroll
            for (int i = 0; i < 4; ++i) {
                float4 v = src[i];
                accv[4 * i + 0] += v.x; accv[4 * i + 1] += v.y;
                accv[4 * i + 2] += v.z; accv[4 * i + 3] += v.w;
            }
        }
#pragma unroll
        for (int j = 0; j < 16; ++j) lds[r * 78 + c0 + j] = f2b(accv[j]);
    }
    __syncthreads();
    {
        const int d = t >> 2, m0 = (t & 3) * 16;
        ushort* dst = St + ((size_t)b * DD + dt * 64 + d) * MM + mt * 64 + m0;
#pragma unroll
        for (int j = 0; j < 16; ++j) dst[j] = lds[(m0 + j) * 78 + d];
    }
}

// ---------- Z[b][m] = sum_kl phi_kT[b][m][kl] ; one wave per row ----------
__global__ __launch_bounds__(256) void z_kernel(const ushort* __restrict__ PhiKT,
                                                float* __restrict__ Z) {
    const int row = blockIdx.x * 4 + (threadIdx.x >> 6);   // b*256 + m
    const int lane = threadIdx.x & 63;
    const int b = row >> 8, m = row & 255;
    const ushort* p = PhiKT + ((size_t)b << 21) + ((size_t)m << 13);
    float s = 0.f;
#pragma unroll
    for (int i = 0; i < 16; ++i) {
        s16x8 v = *(const s16x8*)(p + (size_t)(i * 64 + lane) * 8);
#pragma unroll
        for (int j = 0; j < 8; ++j) s += b2f((ushort)v[j]);
    }
#pragma unroll
    for (int off = 32; off; off >>= 1) s += __shfl_down(s, off);
    if (lane == 0) Z[row] = s;
}

// ---------- den[lg] = phi_q[lg,:] . Z[b,:] ; one wave per row ----------
__global__ __launch_bounds__(256) void den_kernel(const ushort* __restrict__ PhiQ,
                                                  const float* __restrict__ Z,
                                                  float* __restrict__ Den) {
    const int row = blockIdx.x * 4 + (threadIdx.x >> 6);
    const int lane = threadIdx.x & 63;
    const int b = row >> 11;
    s16x4 q = *(const s16x4*)(PhiQ + (size_t)row * MM + lane * 4);
    float4 z = *(const float4*)(Z + (size_t)b * MM + lane * 4);
    float s = b2f((ushort)q[0]) * z.x + b2f((ushort)q[1]) * z.y +
              b2f((ushort)q[2]) * z.z + b2f((ushort)q[3]) * z.w;
#pragma unroll
    for (int off = 32; off; off >>= 1) s += __shfl_down(s, off);
    if (lane == 0) Den[row] = s;
}

// ---------- out: num = phi_q · S ; f = num/(den+eps); amp = content + f ----------
__global__ __launch_bounds__(256) void out_gemm(const ushort* __restrict__ PhiQ,
                                                const ushort* __restrict__ St,
                                                const float* __restrict__ Den,
                                                const float* __restrict__ Content,
                                                float* __restrict__ Amp,
                                                float* __restrict__ Fa) {
    __shared__ __align__(16) ushort sA[128 * 32];
    __shared__ __align__(16) ushort sB[128 * 32];
    f32x4 acc[4][4] = {};
    const int b = blockIdx.z;
    const int rowbase = blockIdx.x * 128;   // l local
    const int colbase = blockIdx.y * 128;   // d
    const ushort* A = PhiQ + (size_t)b * LL * MM;
    const ushort* B = St + (size_t)b * DD * MM;
    gemm128(A, MM, B, MM, rowbase, colbase, 0, MM, sA, sB, acc);

    const int t = threadIdx.x, l = t & 63, w = t >> 6;
    const int wr = (w >> 1) * 64, wc = (w & 1) * 64, fr = l & 15, fg = l >> 4;
#pragma unroll
    for (int mi = 0; mi < 4; ++mi)
#pragma unroll
        for (int rr = 0; rr < 4; ++rr) {
            const int lg = b * LL + rowbase + wr + mi * 16 + fg * 4 + rr;
            const float inv = 1.0f / (Den[lg] + EPSV);
#pragma unroll
            for (int ni = 0; ni < 4; ++ni) {
                const int d = colbase + wc + ni * 16 + fr;
                const size_t idx = (size_t)lg * DD + d;
                const float f = acc[mi][ni][rr] * inv;
                Fa[idx] = f;
                Amp[idx] = Content[idx] + f;
            }
        }
}

extern "C" void kernel_launch(void* const* d_in, const int* in_sizes, int n_in,
                              void* d_out, int out_size, void* d_ws, size_t ws_size,
                              hipStream_t stream) {
    const float* content = (const float*)d_in[0];   // [8,2048,512]
    const float* style   = (const float*)d_in[1];   // [8,4,2048,512] -> [65536,512]
    const float* Wm      = (const float*)d_in[2];   // [512,256]
    float* amp = (float*)d_out;
    float* fa  = (float*)d_out + (size_t)BB * LL * DD;

    // styleT (bf16, [b][d][kl], 67 MB) lives in d_out — scratch until out_gemm
    // overwrites it at the end.
    ushort* styleT = (ushort*)d_out;

    // ---- workspace layout ----
    float* wsf   = (float*)d_ws;
    float* Spart = wsf;                                   // 8 * 1,048,576 f = 32 MB
    float* sq_k  = Spart + (size_t)NSPLIT * BB * MM * DD; // 65,536 f
    float* sq_q  = sq_k + (size_t)BB * KLT;               // 16,384 f
    float* Zbuf  = sq_q + (size_t)BB * LL;                // 2,048 f
    float* den   = Zbuf + (size_t)BB * MM;                // 16,384 f
    ushort* wsu     = (ushort*)(den + (size_t)BB * LL);
    ushort* style_b = wsu;                                 // 33,554,432 u (67 MB)
    ushort* cont_b  = style_b + (size_t)BB * KLT * DD;     //  8,388,608 u
    ushort* Wt      = cont_b + (size_t)BB * LL * DD;       //    131,072 u
    ushort* phi_kT  = Wt + (size_t)MM * DD;                // 16,777,216 u
    ushort* phi_q   = phi_kT + (size_t)BB * MM * KLT;      //  4,194,304 u
    ushort* St      = phi_q + (size_t)BB * LL * MM;        //  1,048,576 u

    // zero only sq_k (atomic partial target)
    hipMemsetAsync(sq_k, 0, (size_t)BB * KLT * sizeof(float), stream);

    prep_w<<<dim3(8, 4), 256, 0, stream>>>(Wm, Wt);
    convert_rows<<<(BB * LL) / 4, 256, 0, stream>>>(content, cont_b, sq_q);
    conv_style<<<dim3(KLT / 64, DD / 64, BB), 256, 0, stream>>>(style, style_b, styleT, sq_k);

    phikt_gemm<<<dim3((BB * KLT) / 128, MM / 128), 256, 0, stream>>>(Wt, style_b, sq_k, phi_kT);
    phiq_gemm<<<dim3((BB * LL) / 128, MM / 128), 256, 0, stream>>>(cont_b, Wt, sq_q, phi_q);

    z_kernel<<<(BB * MM) / 4, 256, 0, stream>>>(phi_kT, Zbuf);
    s_gemm<<<dim3(MM / 128, DD / 128, BB * NSPLIT), 256, 0, stream>>>(phi_kT, styleT, Spart);
    s_fin<<<dim3(MM / 64, DD / 64, BB), 256, 0, stream>>>(Spart, St);

    den_kernel<<<(BB * LL) / 4, 256, 0, stream>>>(phi_q, Zbuf, den);
    out_gemm<<<dim3(LL / 128, DD / 128, BB), 256, 0, stream>>>(phi_q, St, den, content, amp, fa);
}

// Round 6
// 416.282 us; speedup vs baseline: 1.9964x; 1.0064x over previous
//
#include <hip/hip_runtime.h>
#include <hip/hip_bf16.h>
#include <math.h>

typedef short  s16x8 __attribute__((ext_vector_type(8)));
typedef short  s16x4 __attribute__((ext_vector_type(4)));
typedef float  f32x4 __attribute__((ext_vector_type(4)));

#define DD 512      // feature dim d
#define MM 256      // random features m
#define BB 8
#define LL 2048
#define KLT 8192    // K*L style rows per batch
#define NSPLIT 8    // split-K for s_gemm

#define S1f     0.21022410381342864f   // 512^-0.25
#define INV2SDf 0.02209708691207961f   // 1/(2*sqrt(512))
#define S2f     0.0625f                // 256^-0.5
#define EPSV    1e-8f

__device__ __forceinline__ ushort f2b(float f) {
    __hip_bfloat16 h = __float2bfloat16(f);
    return *reinterpret_cast<ushort*>(&h);
}
__device__ __forceinline__ float b2f(ushort u) {
    union { unsigned u32; float f; } x; x.u32 = ((unsigned)u) << 16; return x.f;
}

// async global->LDS, 16 B per lane, linear dest (wave-uniform base + lane*16)
__device__ __forceinline__ void gl_lds16(const ushort* g, ushort* l) {
    __builtin_amdgcn_global_load_lds(
        (const __attribute__((address_space(1))) unsigned int*)(const void*)g,
        (__attribute__((address_space(3))) unsigned int*)(void*)l,
        16, 0, 0);
}

// ---------- coalesced fp32 -> bf16 convert + per-row sq (content) ----------
__global__ __launch_bounds__(256) void convert_rows(const float* __restrict__ X,
                                                    ushort* __restrict__ Xb,
                                                    float* __restrict__ Sq) {
    const int row  = blockIdx.x * 4 + (threadIdx.x >> 6);
    const int lane = threadIdx.x & 63;
    const float4* src = (const float4*)(X + (size_t)row * DD);
    float4 v0 = src[lane];
    float4 v1 = src[lane + 64];
    float s = v0.x * v0.x + v0.y * v0.y + v0.z * v0.z + v0.w * v0.w
            + v1.x * v1.x + v1.y * v1.y + v1.z * v1.z + v1.w * v1.w;
    s16x4* dst = (s16x4*)(Xb + (size_t)row * DD);
    s16x4 o0, o1;
    o0[0] = (short)f2b(v0.x); o0[1] = (short)f2b(v0.y);
    o0[2] = (short)f2b(v0.z); o0[3] = (short)f2b(v0.w);
    o1[0] = (short)f2b(v1.x); o1[1] = (short)f2b(v1.y);
    o1[2] = (short)f2b(v1.z); o1[3] = (short)f2b(v1.w);
    dst[lane]      = o0;
    dst[lane + 64] = o1;
#pragma unroll
    for (int off = 32; off; off >>= 1) s += __shfl_down(s, off);
    if (lane == 0) Sq[row] = s * INV2SDf;
}

// ---------- fused style: fp32 -> bf16 [kl][d], bf16 [d][kl], sq partials ----------
__global__ __launch_bounds__(256) void conv_style(const float* __restrict__ X,
                                                  ushort* __restrict__ Xb,
                                                  ushort* __restrict__ XT,
                                                  float* __restrict__ Sq) {
    __shared__ ushort lds[64 * 72];
    const int t = threadIdx.x;
    const int klt = blockIdx.x, dt = blockIdx.y, b = blockIdx.z;
    const int r = t >> 2, c0 = (t & 3) * 16;
    const size_t rowg = (size_t)b * KLT + klt * 64 + r;
    const float4* src = (const float4*)(X + rowg * DD + dt * 64 + c0);
    float s = 0.f;
    s16x8 o0, o1;
#pragma unroll
    for (int i = 0; i < 2; ++i) {
        float4 v = src[2 * i], w = src[2 * i + 1];
        s += v.x * v.x + v.y * v.y + v.z * v.z + v.w * v.w
           + w.x * w.x + w.y * w.y + w.z * w.z + w.w * w.w;
        s16x8 o;
        o[0] = (short)f2b(v.x); o[1] = (short)f2b(v.y);
        o[2] = (short)f2b(v.z); o[3] = (short)f2b(v.w);
        o[4] = (short)f2b(w.x); o[5] = (short)f2b(w.y);
        o[6] = (short)f2b(w.z); o[7] = (short)f2b(w.w);
        if (i == 0) o0 = o; else o1 = o;
    }
    ushort* dstb = Xb + rowg * DD + dt * 64 + c0;
    *(s16x8*)(dstb)     = o0;
    *(s16x8*)(dstb + 8) = o1;
    *(s16x8*)(lds + r * 72 + c0)     = o0;
    *(s16x8*)(lds + r * 72 + c0 + 8) = o1;
    s += __shfl_xor(s, 1);
    s += __shfl_xor(s, 2);
    if ((t & 3) == 0) atomicAdd(&Sq[rowg], s * INV2SDf);
    __syncthreads();
    const int d = t >> 2, k0c = (t & 3) * 16;
    s16x8 t0, t1;
#pragma unroll
    for (int j = 0; j < 8; ++j) t0[j] = (short)lds[(k0c + j) * 72 + d];
#pragma unroll
    for (int j = 0; j < 8; ++j) t1[j] = (short)lds[(k0c + 8 + j) * 72 + d];
    ushort* dstT = XT + ((size_t)b * DD + dt * 64 + d) * KLT + klt * 64 + k0c;
    *(s16x8*)(dstT)     = t0;
    *(s16x8*)(dstT + 8) = t1;
}

// ---------- Wt[m][d] = bf16(W[d][m]) ----------
__global__ __launch_bounds__(256) void prep_w(const float* __restrict__ W,
                                              ushort* __restrict__ Wt) {
    __shared__ ushort lds[64 * 78];
    const int t = threadIdx.x;
    const int dt = blockIdx.x;   // 0..7
    const int mt = blockIdx.y;   // 0..3
    {
        int r = t >> 2, c0 = (t & 3) * 16;
        const float4* src = (const float4*)(W + (size_t)(dt * 64 + r) * MM + mt * 64 + c0);
#pragma unroll
        for (int i = 0; i < 4; ++i) {
            float4 v = src[i];
            lds[r * 78 + c0 + 4 * i + 0] = f2b(v.x);
            lds[r * 78 + c0 + 4 * i + 1] = f2b(v.y);
            lds[r * 78 + c0 + 4 * i + 2] = f2b(v.z);
            lds[r * 78 + c0 + 4 * i + 3] = f2b(v.w);
        }
    }
    __syncthreads();
    {
        int m = t >> 2, d0 = (t & 3) * 16;
        ushort* dst = Wt + (size_t)(mt * 64 + m) * DD + dt * 64 + d0;
#pragma unroll
        for (int j = 0; j < 16; ++j) dst[j] = lds[(d0 + j) * 78 + m];
    }
}

// ---------- 128x128 BK=32 bf16 MFMA core, global_load_lds staging ----------
__device__ __forceinline__ void gemm128(const ushort* __restrict__ A, int lda,
                                        const ushort* __restrict__ B, int ldb,
                                        int rowbase, int colbase, int k0, int k1,
                                        ushort* sA, ushort* sB, f32x4 acc[4][4]) {
    const int t = threadIdx.x;
    const int l = t & 63, w = t >> 6;
    const int wr = (w >> 1) * 64, wc = (w & 1) * 64;
    const int fr = l & 15, fg = l >> 4;
    const int lrow = l >> 2, lk = (l & 3) * 8;

    for (int kk = k0; kk < k1; kk += 32) {
        gl_lds16(A + (size_t)(rowbase + w * 16 + lrow) * lda + kk + lk,
                 sA + (w * 16) * 32);
        gl_lds16(A + (size_t)(rowbase + (w + 4) * 16 + lrow) * lda + kk + lk,
                 sA + ((w + 4) * 16) * 32);
        gl_lds16(B + (size_t)(colbase + w * 16 + lrow) * ldb + kk + lk,
                 sB + (w * 16) * 32);
        gl_lds16(B + (size_t)(colbase + (w + 4) * 16 + lrow) * ldb + kk + lk,
                 sB + ((w + 4) * 16) * 32);
        __syncthreads();
        s16x8 a[4], b[4];
#pragma unroll
        for (int mi = 0; mi < 4; ++mi)
            a[mi] = *(const s16x8*)(sA + (wr + mi * 16 + fr) * 32 + fg * 8);
#pragma unroll
        for (int ni = 0; ni < 4; ++ni)
            b[ni] = *(const s16x8*)(sB + (wc + ni * 16 + fr) * 32 + fg * 8);
#pragma unroll
        for (int mi = 0; mi < 4; ++mi)
#pragma unroll
            for (int ni = 0; ni < 4; ++ni)
                acc[mi][ni] = __builtin_amdgcn_mfma_f32_16x16x32_bf16(
                    a[mi], b[ni], acc[mi][ni], 0, 0, 0);
        __syncthreads();
    }
}

// ---------- phi_kT: C[m, kl] = Wt · style^T, exp epilogue, LDS-retiled store ----------
__global__ __launch_bounds__(256) void phikt_gemm(const ushort* __restrict__ Wt,
                                                  const ushort* __restrict__ Sb,
                                                  const float* __restrict__ sqk,
                                                  ushort* __restrict__ PhiKT) {
    __shared__ __align__(16) ushort smem[128 * 64];   // 16 KB: sA|sB, reused by epilogue
    ushort* sA = smem;
    ushort* sB = smem + 128 * 32;
    f32x4 acc[4][4] = {};
    const int rowbase = blockIdx.y * 128;   // m
    const int colbase = blockIdx.x * 128;   // kl global
    gemm128(Wt, DD, Sb, DD, rowbase, colbase, 0, DD, sA, sB, acc);

    const int t = threadIdx.x, l = t & 63, w = t >> 6;
    const int wr = (w >> 1) * 64, wc = (w & 1) * 64, fr = l & 15, fg = l >> 4;
    const int b = colbase >> 13;
    const int kll_base = colbase & (KLT - 1);
    float sqv[4];
#pragma unroll
    for (int ni = 0; ni < 4; ++ni) sqv[ni] = sqk[colbase + wc + ni * 16 + fr];

    for (int c = 0; c < 2; ++c) {           // 64-row bf16 chunks
        if ((wr >> 6) == c) {
#pragma unroll
            for (int mi = 0; mi < 4; ++mi)
#pragma unroll
                for (int ni = 0; ni < 4; ++ni)
#pragma unroll
                    for (int rr = 0; rr < 4; ++rr)
                        smem[(mi * 16 + fg * 4 + rr) * 128 + wc + ni * 16 + fr] =
                            f2b(__expf(acc[mi][ni][rr] * S1f - sqv[ni]) * S2f);
        }
        __syncthreads();
        {
            const int row = t >> 2, col0 = (t & 3) * 32;
            const int m = rowbase + c * 64 + row;
            ushort* dst = PhiKT + ((size_t)b << 21) + ((size_t)m << 13) + kll_base + col0;
#pragma unroll
            for (int j = 0; j < 4; ++j)
                *(s16x8*)(dst + 8 * j) = *(s16x8*)&smem[row * 128 + col0 + 8 * j];
        }
        __syncthreads();
    }
}

// ---------- phi_q: C[l, m] = content · W, exp epilogue, LDS-retiled store ----------
__global__ __launch_bounds__(256) void phiq_gemm(const ushort* __restrict__ Cb,
                                                 const ushort* __restrict__ Wt,
                                                 const float* __restrict__ sqq,
                                                 ushort* __restrict__ PhiQ) {
    __shared__ __align__(16) ushort smem[128 * 64];
    ushort* sA = smem;
    ushort* sB = smem + 128 * 32;
    f32x4 acc[4][4] = {};
    const int rowbase = blockIdx.x * 128;   // l global
    const int colbase = blockIdx.y * 128;   // m
    gemm128(Cb, DD, Wt, DD, rowbase, colbase, 0, DD, sA, sB, acc);

    const int t = threadIdx.x, l = t & 63, w = t >> 6;
    const int wr = (w >> 1) * 64, wc = (w & 1) * 64, fr = l & 15, fg = l >> 4;
    float sqr[4][4];
#pragma unroll
    for (int mi = 0; mi < 4; ++mi)
#pragma unroll
        for (int rr = 0; rr < 4; ++rr)
            sqr[mi][rr] = sqq[rowbase + wr + mi * 16 + fg * 4 + rr];

    for (int c = 0; c < 2; ++c) {
        if ((wr >> 6) == c) {
#pragma unroll
            for (int mi = 0; mi < 4; ++mi)
#pragma unroll
                for (int ni = 0; ni < 4; ++ni)
#pragma unroll
                    for (int rr = 0; rr < 4; ++rr)
                        smem[(mi * 16 + fg * 4 + rr) * 128 + wc + ni * 16 + fr] =
                            f2b(__expf(acc[mi][ni][rr] * S1f - sqr[mi][rr]) * S2f);
        }
        __syncthreads();
        {
            const int row = t >> 2, col0 = (t & 3) * 32;
            const int lg = rowbase + c * 64 + row;
            ushort* dst = PhiQ + (size_t)lg * MM + colbase + col0;
#pragma unroll
            for (int j = 0; j < 4; ++j)
                *(s16x8*)(dst + 8 * j) = *(s16x8*)&smem[row * 128 + col0 + 8 * j];
        }
        __syncthreads();
    }
}

// ---------- S partials: Spart[split][b][m][d], LDS-retiled fp32 store ----------
__global__ __launch_bounds__(256) void s_gemm(const ushort* __restrict__ PhiKT,
                                              const ushort* __restrict__ StyT,
                                              float* __restrict__ Spart) {
    __shared__ __align__(16) ushort smem[128 * 64];
    ushort* sA = smem;
    ushort* sB = smem + 128 * 32;
    f32x4 acc[4][4] = {};
    const int b = blockIdx.z >> 3, split = blockIdx.z & 7;
    const int rowbase = blockIdx.x * 128;   // m
    const int colbase = blockIdx.y * 128;   // d
    const ushort* A = PhiKT + ((size_t)b << 21);
    const ushort* B = StyT + (size_t)b * DD * KLT;
    gemm128(A, KLT, B, KLT, rowbase, colbase, split * 1024, split * 1024 + 1024,
            sA, sB, acc);

    const int t = threadIdx.x, l = t & 63, w = t >> 6;
    const int wr = (w >> 1) * 64, wc = (w & 1) * 64, fr = l & 15, fg = l >> 4;
    float* ldsf = (float*)smem;             // 32 x 128 fp32 = 16 KB
    float* out = Spart + (size_t)(split * BB + b) * MM * DD;

    for (int c = 0; c < 4; ++c) {           // 32-row fp32 chunks
        const bool part = (wr == 0) ? (c < 2) : (c >= 2);
        const int c2 = (wr == 0) ? c : c - 2;
        if (part) {
#pragma unroll
            for (int mi2 = 0; mi2 < 2; ++mi2) {
                const int mi = 2 * c2 + mi2;
#pragma unroll
                for (int ni = 0; ni < 4; ++ni)
#pragma unroll
                    for (int rr = 0; rr < 4; ++rr)
                        ldsf[(mi2 * 16 + fg * 4 + rr) * 128 + wc + ni * 16 + fr] =
                            acc[mi][ni][rr];
            }
        }
        __syncthreads();
        {
            const int row = t >> 3, col0 = (t & 7) * 16;
            const int m = rowbase + c * 32 + row;
            float* dst = out + (size_t)m * DD + colbase + col0;
#pragma unroll
            for (int j = 0; j < 4; ++j)
                *(float4*)(dst + 4 * j) = *(float4*)&ldsf[row * 128 + col0 + 4 * j];
        }
        __syncthreads();
    }
}

// ---------- St[b][d][m] = bf16(sum_split Spart) ----------
__global__ __launch_bounds__(256) void s_fin(const float* __restrict__ Sp,
                                             ushort* __restrict__ St) {
    __shared__ ushort lds[64 * 78];
    const int t = threadIdx.x;
    const int mt = blockIdx.x, dt = blockIdx.y, b = blockIdx.z;
    {
        const int r = t >> 2, c0 = (t & 3) * 16;
        float accv[16];
#pragma unroll
        for (int j = 0; j < 16; ++j) accv[j] = 0.f;
#pragma unroll
        for (int sp = 0; sp < NSPLIT; ++sp) {
            const float4* src = (const float4*)(Sp +
                ((size_t)(sp * BB + b) * MM + mt * 64 + r) * DD + dt * 64 + c0);
#pragma unroll
            for (int i = 0; i < 4; ++i) {
                float4 v = src[i];
                accv[4 * i + 0] += v.x; accv[4 * i + 1] += v.y;
                accv[4 * i + 2] += v.z; accv[4 * i + 3] += v.w;
            }
        }
#pragma unroll
        for (int j = 0; j < 16; ++j) lds[r * 78 + c0 + j] = f2b(accv[j]);
    }
    __syncthreads();
    {
        const int d = t >> 2, m0 = (t & 3) * 16;
        ushort* dst = St + ((size_t)b * DD + dt * 64 + d) * MM + mt * 64 + m0;
#pragma unroll
        for (int j = 0; j < 16; ++j) dst[j] = lds[(m0 + j) * 78 + d];
    }
}

// ---------- Z[b][m] = sum_kl phi_kT[b][m][kl] ----------
__global__ __launch_bounds__(256) void z_kernel(const ushort* __restrict__ PhiKT,
                                                float* __restrict__ Z) {
    const int row = blockIdx.x * 4 + (threadIdx.x >> 6);
    const int lane = threadIdx.x & 63;
    const int b = row >> 8, m = row & 255;
    const ushort* p = PhiKT + ((size_t)b << 21) + ((size_t)m << 13);
    float s = 0.f;
#pragma unroll
    for (int i = 0; i < 16; ++i) {
        s16x8 v = *(const s16x8*)(p + (size_t)(i * 64 + lane) * 8);
#pragma unroll
        for (int j = 0; j < 8; ++j) s += b2f((ushort)v[j]);
    }
#pragma unroll
    for (int off = 32; off; off >>= 1) s += __shfl_down(s, off);
    if (lane == 0) Z[row] = s;
}

// ---------- den[lg] = phi_q[lg,:] . Z[b,:] ----------
__global__ __launch_bounds__(256) void den_kernel(const ushort* __restrict__ PhiQ,
                                                  const float* __restrict__ Z,
                                                  float* __restrict__ Den) {
    const int row = blockIdx.x * 4 + (threadIdx.x >> 6);
    const int lane = threadIdx.x & 63;
    const int b = row >> 11;
    s16x4 q = *(const s16x4*)(PhiQ + (size_t)row * MM + lane * 4);
    float4 z = *(const float4*)(Z + (size_t)b * MM + lane * 4);
    float s = b2f((ushort)q[0]) * z.x + b2f((ushort)q[1]) * z.y +
              b2f((ushort)q[2]) * z.z + b2f((ushort)q[3]) * z.w;
#pragma unroll
    for (int off = 32; off; off >>= 1) s += __shfl_down(s, off);
    if (lane == 0) Den[row] = s;
}

// ---------- out: num = phi_q · S ; LDS-retiled fp32 epilogue ----------
__global__ __launch_bounds__(256) void out_gemm(const ushort* __restrict__ PhiQ,
                                                const ushort* __restrict__ St,
                                                const float* __restrict__ Den,
                                                const float* __restrict__ Content,
                                                float* __restrict__ Amp,
                                                float* __restrict__ Fa) {
    __shared__ __align__(16) ushort smem[128 * 64];
    ushort* sA = smem;
    ushort* sB = smem + 128 * 32;
    f32x4 acc[4][4] = {};
    const int b = blockIdx.z;
    const int rowbase = blockIdx.x * 128;   // l local
    const int colbase = blockIdx.y * 128;   // d
    const ushort* A = PhiQ + (size_t)b * LL * MM;
    const ushort* B = St + (size_t)b * DD * MM;
    gemm128(A, MM, B, MM, rowbase, colbase, 0, MM, sA, sB, acc);

    const int t = threadIdx.x, l = t & 63, w = t >> 6;
    const int wr = (w >> 1) * 64, wc = (w & 1) * 64, fr = l & 15, fg = l >> 4;
    float* ldsf = (float*)smem;

    for (int c = 0; c < 4; ++c) {           // 32-row fp32 chunks
        const bool part = (wr == 0) ? (c < 2) : (c >= 2);
        const int c2 = (wr == 0) ? c : c - 2;
        if (part) {
#pragma unroll
            for (int mi2 = 0; mi2 < 2; ++mi2) {
                const int mi = 2 * c2 + mi2;
#pragma unroll
                for (int ni = 0; ni < 4; ++ni)
#pragma unroll
                    for (int rr = 0; rr < 4; ++rr)
                        ldsf[(mi2 * 16 + fg * 4 + rr) * 128 + wc + ni * 16 + fr] =
                            acc[mi][ni][rr];
            }
        }
        __syncthreads();
        {
            const int row = t >> 3, col0 = (t & 7) * 16;
            const int lg = b * LL + rowbase + c * 32 + row;
            const float inv = 1.0f / (Den[lg] + EPSV);
            const size_t base = (size_t)lg * DD + colbase + col0;
#pragma unroll
            for (int j = 0; j < 4; ++j) {
                float4 v = *(float4*)&ldsf[row * 128 + col0 + 4 * j];
                float4 f4 = {v.x * inv, v.y * inv, v.z * inv, v.w * inv};
                float4 c4 = *(const float4*)&Content[base + 4 * j];
                *(float4*)&Fa[base + 4 * j] = f4;
                float4 a4 = {c4.x + f4.x, c4.y + f4.y, c4.z + f4.z, c4.w + f4.w};
                *(float4*)&Amp[base + 4 * j] = a4;
            }
        }
        __syncthreads();
    }
}

extern "C" void kernel_launch(void* const* d_in, const int* in_sizes, int n_in,
                              void* d_out, int out_size, void* d_ws, size_t ws_size,
                              hipStream_t stream) {
    const float* content = (const float*)d_in[0];   // [8,2048,512]
    const float* style   = (const float*)d_in[1];   // [8,4,2048,512]
    const float* Wm      = (const float*)d_in[2];   // [512,256]
    float* amp = (float*)d_out;
    float* fa  = (float*)d_out + (size_t)BB * LL * DD;

    // styleT (bf16, [b][d][kl], 67 MB) lives in d_out — scratch until out_gemm.
    ushort* styleT = (ushort*)d_out;

    // ---- workspace layout ----
    float* wsf   = (float*)d_ws;
    float* Spart = wsf;                                   // 32 MB
    float* sq_k  = Spart + (size_t)NSPLIT * BB * MM * DD;
    float* sq_q  = sq_k + (size_t)BB * KLT;
    float* Zbuf  = sq_q + (size_t)BB * LL;
    float* den   = Zbuf + (size_t)BB * MM;
    ushort* wsu     = (ushort*)(den + (size_t)BB * LL);
    ushort* style_b = wsu;                                 // 67 MB
    ushort* cont_b  = style_b + (size_t)BB * KLT * DD;
    ushort* Wt      = cont_b + (size_t)BB * LL * DD;
    ushort* phi_kT  = Wt + (size_t)MM * DD;
    ushort* phi_q   = phi_kT + (size_t)BB * MM * KLT;
    ushort* St      = phi_q + (size_t)BB * LL * MM;

    hipMemsetAsync(sq_k, 0, (size_t)BB * KLT * sizeof(float), stream);

    prep_w<<<dim3(8, 4), 256, 0, stream>>>(Wm, Wt);
    convert_rows<<<(BB * LL) / 4, 256, 0, stream>>>(content, cont_b, sq_q);
    conv_style<<<dim3(KLT / 64, DD / 64, BB), 256, 0, stream>>>(style, style_b, styleT, sq_k);

    phikt_gemm<<<dim3((BB * KLT) / 128, MM / 128), 256, 0, stream>>>(Wt, style_b, sq_k, phi_kT);
    phiq_gemm<<<dim3((BB * LL) / 128, MM / 128), 256, 0, stream>>>(cont_b, Wt, sq_q, phi_q);

    z_kernel<<<(BB * MM) / 4, 256, 0, stream>>>(phi_kT, Zbuf);
    s_gemm<<<dim3(MM / 128, DD / 128, BB * NSPLIT), 256, 0, stream>>>(phi_kT, styleT, Spart);
    s_fin<<<dim3(MM / 64, DD / 64, BB), 256, 0, stream>>>(Spart, St);

    den_kernel<<<(BB * LL) / 4, 256, 0, stream>>>(phi_q, Zbuf, den);
    out_gemm<<<dim3(LL / 128, DD / 128, BB), 256, 0, stream>>>(phi_q, St, den, content, amp, fa);
}

// Round 7
// 409.488 us; speedup vs baseline: 2.0296x; 1.0166x over previous
//
#include <hip/hip_runtime.h>
#include <hip/hip_bf16.h>
#include <math.h>

typedef short  s16x8 __attribute__((ext_vector_type(8)));
typedef short  s16x4 __attribute__((ext_vector_type(4)));
typedef float  f32x4 __attribute__((ext_vector_type(4)));

#define DD 512      // feature dim d
#define MM 256      // random features m
#define BB 8
#define LL 2048
#define KLT 8192    // K*L style rows per batch
#define NSPLIT 8    // split-K for s_gemm

#define S1f     0.21022410381342864f   // 512^-0.25
#define INV2SDf 0.02209708691207961f   // 1/(2*sqrt(512))
#define S2f     0.0625f                // 256^-0.5
#define EPSV    1e-8f

__device__ __forceinline__ ushort f2b(float f) {
    __hip_bfloat16 h = __float2bfloat16(f);
    return *reinterpret_cast<ushort*>(&h);
}
__device__ __forceinline__ float b2f(ushort u) {
    union { unsigned u32; float f; } x; x.u32 = ((unsigned)u) << 16; return x.f;
}

// async global->LDS, 16 B per lane, linear dest (wave-uniform base + lane*16)
__device__ __forceinline__ void gl_lds16(const ushort* g, ushort* l) {
    __builtin_amdgcn_global_load_lds(
        (const __attribute__((address_space(1))) unsigned int*)(const void*)g,
        (__attribute__((address_space(3))) unsigned int*)(void*)l,
        16, 0, 0);
}

// ---------- coalesced fp32 -> bf16 convert + per-row sq (content) ----------
__global__ __launch_bounds__(256) void convert_rows(const float* __restrict__ X,
                                                    ushort* __restrict__ Xb,
                                                    float* __restrict__ Sq) {
    const int row  = blockIdx.x * 4 + (threadIdx.x >> 6);
    const int lane = threadIdx.x & 63;
    const float4* src = (const float4*)(X + (size_t)row * DD);
    float4 v0 = src[lane];
    float4 v1 = src[lane + 64];
    float s = v0.x * v0.x + v0.y * v0.y + v0.z * v0.z + v0.w * v0.w
            + v1.x * v1.x + v1.y * v1.y + v1.z * v1.z + v1.w * v1.w;
    s16x4* dst = (s16x4*)(Xb + (size_t)row * DD);
    s16x4 o0, o1;
    o0[0] = (short)f2b(v0.x); o0[1] = (short)f2b(v0.y);
    o0[2] = (short)f2b(v0.z); o0[3] = (short)f2b(v0.w);
    o1[0] = (short)f2b(v1.x); o1[1] = (short)f2b(v1.y);
    o1[2] = (short)f2b(v1.z); o1[3] = (short)f2b(v1.w);
    dst[lane]      = o0;
    dst[lane + 64] = o1;
#pragma unroll
    for (int off = 32; off; off >>= 1) s += __shfl_down(s, off);
    if (lane == 0) Sq[row] = s * INV2SDf;
}

// ---------- fused style convert+transpose: 64 rows x full 512 d per block ----------
// Reads fp32 fully coalesced (2 KB rows). Writes style_b [kl][d] + styleT [d][kl] + sq.
#define CS_PITCH 514   // ushorts; stride 257 dwords (odd) -> conflict-free column reads
__global__ __launch_bounds__(256) void conv_style(const float* __restrict__ X,
                                                  ushort* __restrict__ Xb,
                                                  ushort* __restrict__ XT,
                                                  float* __restrict__ Sq) {
    __shared__ ushort lds[64 * CS_PITCH];   // 65,792 B
    const int t = threadIdx.x;
    const int klt = blockIdx.x;   // 0..127
    const int b   = blockIdx.y;
    const int r = t >> 2;                    // row 0..63
    const int q = t & 3;                     // quad slot
    const size_t rowg = (size_t)b * KLT + klt * 64 + r;
    const float* srcf = X + rowg * DD;
    ushort* dstb = Xb + rowg * DD;
    float s = 0.f;
#pragma unroll
    for (int i = 0; i < 16; ++i) {           // 8 cols per iter, interleaved by quad
        const int col = q * 8 + 32 * i;
        float4 v = *(const float4*)(srcf + col);
        float4 w = *(const float4*)(srcf + col + 4);
        s += v.x * v.x + v.y * v.y + v.z * v.z + v.w * v.w
           + w.x * w.x + w.y * w.y + w.z * w.z + w.w * w.w;
        s16x8 o;
        o[0] = (short)f2b(v.x); o[1] = (short)f2b(v.y);
        o[2] = (short)f2b(v.z); o[3] = (short)f2b(v.w);
        o[4] = (short)f2b(w.x); o[5] = (short)f2b(w.y);
        o[6] = (short)f2b(w.z); o[7] = (short)f2b(w.w);
        *(s16x8*)(dstb + col) = o;
        *(s16x8*)(lds + r * CS_PITCH + col) = o;
    }
    s += __shfl_xor(s, 1);
    s += __shfl_xor(s, 2);
    if (q == 0) Sq[rowg] = s * INV2SDf;      // non-atomic: full row in this block
    __syncthreads();
    // transpose phase: 2 d-rows per thread, conflict-free column gather
#pragma unroll
    for (int dd2 = 0; dd2 < 2; ++dd2) {
        const int d = t + dd2 * 256;
        s16x8 o[8];
#pragma unroll
        for (int jc = 0; jc < 8; ++jc)
#pragma unroll
            for (int je = 0; je < 8; ++je)
                o[jc][je] = (short)lds[(jc * 8 + je) * CS_PITCH + d];
        ushort* dst = XT + ((size_t)b * DD + d) * KLT + klt * 64;
#pragma unroll
        for (int k = 0; k < 8; ++k) *(s16x8*)(dst + 8 * k) = o[k];
    }
}

// ---------- Wt[m][d] = bf16(W[d][m]) ----------
__global__ __launch_bounds__(256) void prep_w(const float* __restrict__ W,
                                              ushort* __restrict__ Wt) {
    __shared__ ushort lds[64 * 78];
    const int t = threadIdx.x;
    const int dt = blockIdx.x;   // 0..7
    const int mt = blockIdx.y;   // 0..3
    {
        int r = t >> 2, c0 = (t & 3) * 16;
        const float4* src = (const float4*)(W + (size_t)(dt * 64 + r) * MM + mt * 64 + c0);
#pragma unroll
        for (int i = 0; i < 4; ++i) {
            float4 v = src[i];
            lds[r * 78 + c0 + 4 * i + 0] = f2b(v.x);
            lds[r * 78 + c0 + 4 * i + 1] = f2b(v.y);
            lds[r * 78 + c0 + 4 * i + 2] = f2b(v.z);
            lds[r * 78 + c0 + 4 * i + 3] = f2b(v.w);
        }
    }
    __syncthreads();
    {
        int m = t >> 2, d0 = (t & 3) * 16;
        ushort* dst = Wt + (size_t)(mt * 64 + m) * DD + dt * 64 + d0;
#pragma unroll
        for (int j = 0; j < 16; ++j) dst[j] = lds[(d0 + j) * 78 + m];
    }
}

// ---------- 128x128 BK=32 bf16 MFMA core, global_load_lds staging ----------
__device__ __forceinline__ void gemm128(const ushort* __restrict__ A, int lda,
                                        const ushort* __restrict__ B, int ldb,
                                        int rowbase, int colbase, int k0, int k1,
                                        ushort* sA, ushort* sB, f32x4 acc[4][4]) {
    const int t = threadIdx.x;
    const int l = t & 63, w = t >> 6;
    const int wr = (w >> 1) * 64, wc = (w & 1) * 64;
    const int fr = l & 15, fg = l >> 4;
    const int lrow = l >> 2, lk = (l & 3) * 8;

    for (int kk = k0; kk < k1; kk += 32) {
        gl_lds16(A + (size_t)(rowbase + w * 16 + lrow) * lda + kk + lk,
                 sA + (w * 16) * 32);
        gl_lds16(A + (size_t)(rowbase + (w + 4) * 16 + lrow) * lda + kk + lk,
                 sA + ((w + 4) * 16) * 32);
        gl_lds16(B + (size_t)(colbase + w * 16 + lrow) * ldb + kk + lk,
                 sB + (w * 16) * 32);
        gl_lds16(B + (size_t)(colbase + (w + 4) * 16 + lrow) * ldb + kk + lk,
                 sB + ((w + 4) * 16) * 32);
        __syncthreads();
        s16x8 a[4], b[4];
#pragma unroll
        for (int mi = 0; mi < 4; ++mi)
            a[mi] = *(const s16x8*)(sA + (wr + mi * 16 + fr) * 32 + fg * 8);
#pragma unroll
        for (int ni = 0; ni < 4; ++ni)
            b[ni] = *(const s16x8*)(sB + (wc + ni * 16 + fr) * 32 + fg * 8);
#pragma unroll
        for (int mi = 0; mi < 4; ++mi)
#pragma unroll
            for (int ni = 0; ni < 4; ++ni)
                acc[mi][ni] = __builtin_amdgcn_mfma_f32_16x16x32_bf16(
                    a[mi], b[ni], acc[mi][ni], 0, 0, 0);
        __syncthreads();
    }
}

// ---------- phi_kT GEMM + exp epilogue + fused Z column-sum ----------
// XCD-swizzled 1-D grid (1024): each XCD owns one batch's kl range.
__global__ __launch_bounds__(256) void phikt_gemm(const ushort* __restrict__ Wt,
                                                  const ushort* __restrict__ Sb,
                                                  const float* __restrict__ sqk,
                                                  ushort* __restrict__ PhiKT,
                                                  float* __restrict__ Z) {
    __shared__ __align__(16) ushort smem[128 * 64];
    ushort* sA = smem;
    ushort* sB = smem + 128 * 32;
    f32x4 acc[4][4] = {};
    const int z = blockIdx.x;
    const int kl_tile = (z & 7) * 64 + ((z >> 3) >> 1);   // pairs (m=0,1) on same XCD
    const int rowbase = ((z >> 3) & 1) * 128;             // m
    const int colbase = kl_tile * 128;                    // kl global
    gemm128(Wt, DD, Sb, DD, rowbase, colbase, 0, DD, sA, sB, acc);

    const int t = threadIdx.x, l = t & 63, w = t >> 6;
    const int wr = (w >> 1) * 64, wc = (w & 1) * 64, fr = l & 15, fg = l >> 4;
    const int b = colbase >> 13;
    const int kll_base = colbase & (KLT - 1);
    float sqv[4];
#pragma unroll
    for (int ni = 0; ni < 4; ++ni) sqv[ni] = sqk[colbase + wc + ni * 16 + fr];

    for (int c = 0; c < 2; ++c) {           // 64-row bf16 chunks
        if ((wr >> 6) == c) {
#pragma unroll
            for (int mi = 0; mi < 4; ++mi)
#pragma unroll
                for (int ni = 0; ni < 4; ++ni)
#pragma unroll
                    for (int rr = 0; rr < 4; ++rr)
                        smem[(mi * 16 + fg * 4 + rr) * 128 + wc + ni * 16 + fr] =
                            f2b(__expf(acc[mi][ni][rr] * S1f - sqv[ni]) * S2f);
        }
        __syncthreads();
        {
            const int row = t >> 2, col0 = (t & 3) * 32;
            const int m = rowbase + c * 64 + row;
            ushort* dst = PhiKT + ((size_t)b << 21) + ((size_t)m << 13) + kll_base + col0;
            float zp = 0.f;
#pragma unroll
            for (int j = 0; j < 4; ++j) {
                s16x8 v = *(s16x8*)&smem[row * 128 + col0 + 8 * j];
                *(s16x8*)(dst + 8 * j) = v;
#pragma unroll
                for (int e = 0; e < 8; ++e) zp += b2f((ushort)v[e]);
            }
            zp += __shfl_xor(zp, 1);
            zp += __shfl_xor(zp, 2);
            if ((t & 3) == 0) atomicAdd(&Z[b * MM + m], zp);
        }
        __syncthreads();
    }
}

// ---------- phi_q GEMM + exp epilogue (XCD-swizzled 1-D grid 256) ----------
__global__ __launch_bounds__(256) void phiq_gemm(const ushort* __restrict__ Cb,
                                                 const ushort* __restrict__ Wt,
                                                 const float* __restrict__ sqq,
                                                 ushort* __restrict__ PhiQ) {
    __shared__ __align__(16) ushort smem[128 * 64];
    ushort* sA = smem;
    ushort* sB = smem + 128 * 32;
    f32x4 acc[4][4] = {};
    const int z = blockIdx.x;
    const int lt = (z & 7) * 16 + ((z >> 3) >> 1);
    const int rowbase = lt * 128;                 // l global
    const int colbase = ((z >> 3) & 1) * 128;     // m
    gemm128(Cb, DD, Wt, DD, rowbase, colbase, 0, DD, sA, sB, acc);

    const int t = threadIdx.x, l = t & 63, w = t >> 6;
    const int wr = (w >> 1) * 64, wc = (w & 1) * 64, fr = l & 15, fg = l >> 4;
    float sqr[4][4];
#pragma unroll
    for (int mi = 0; mi < 4; ++mi)
#pragma unroll
        for (int rr = 0; rr < 4; ++rr)
            sqr[mi][rr] = sqq[rowbase + wr + mi * 16 + fg * 4 + rr];

    for (int c = 0; c < 2; ++c) {
        if ((wr >> 6) == c) {
#pragma unroll
            for (int mi = 0; mi < 4; ++mi)
#pragma unroll
                for (int ni = 0; ni < 4; ++ni)
#pragma unroll
                    for (int rr = 0; rr < 4; ++rr)
                        smem[(mi * 16 + fg * 4 + rr) * 128 + wc + ni * 16 + fr] =
                            f2b(__expf(acc[mi][ni][rr] * S1f - sqr[mi][rr]) * S2f);
        }
        __syncthreads();
        {
            const int row = t >> 2, col0 = (t & 3) * 32;
            const int lg = rowbase + c * 64 + row;
            ushort* dst = PhiQ + (size_t)lg * MM + colbase + col0;
#pragma unroll
            for (int j = 0; j < 4; ++j)
                *(s16x8*)(dst + 8 * j) = *(s16x8*)&smem[row * 128 + col0 + 8 * j];
        }
        __syncthreads();
    }
}

// ---------- S partials (XCD-swizzled: 8 blocks of one (b,split) per XCD) ----------
__global__ __launch_bounds__(256) void s_gemm(const ushort* __restrict__ PhiKT,
                                              const ushort* __restrict__ StyT,
                                              float* __restrict__ Spart) {
    __shared__ __align__(16) ushort smem[128 * 64];
    ushort* sA = smem;
    ushort* sB = smem + 128 * 32;
    f32x4 acc[4][4] = {};
    const int z = blockIdx.x;
    const int xcd = z & 7, slot = z >> 3;
    const int g = xcd * 8 + (slot >> 3);          // (b,split) group
    const int b = g >> 3, split = g & 7;
    const int rowbase = ((slot >> 2) & 1) * 128;  // m
    const int colbase = (slot & 3) * 128;         // d
    const ushort* A = PhiKT + ((size_t)b << 21);
    const ushort* B = StyT + (size_t)b * DD * KLT;
    gemm128(A, KLT, B, KLT, rowbase, colbase, split * 1024, split * 1024 + 1024,
            sA, sB, acc);

    const int t = threadIdx.x, l = t & 63, w = t >> 6;
    const int wr = (w >> 1) * 64, wc = (w & 1) * 64, fr = l & 15, fg = l >> 4;
    float* ldsf = (float*)smem;
    float* out = Spart + (size_t)(split * BB + b) * MM * DD;

    for (int c = 0; c < 4; ++c) {
        const bool part = (wr == 0) ? (c < 2) : (c >= 2);
        const int c2 = (wr == 0) ? c : c - 2;
        if (part) {
#pragma unroll
            for (int mi2 = 0; mi2 < 2; ++mi2) {
                const int mi = 2 * c2 + mi2;
#pragma unroll
                for (int ni = 0; ni < 4; ++ni)
#pragma unroll
                    for (int rr = 0; rr < 4; ++rr)
                        ldsf[(mi2 * 16 + fg * 4 + rr) * 128 + wc + ni * 16 + fr] =
                            acc[mi][ni][rr];
            }
        }
        __syncthreads();
        {
            const int row = t >> 3, col0 = (t & 7) * 16;
            const int m = rowbase + c * 32 + row;
            float* dst = out + (size_t)m * DD + colbase + col0;
#pragma unroll
            for (int j = 0; j < 4; ++j)
                *(float4*)(dst + 4 * j) = *(float4*)&ldsf[row * 128 + col0 + 4 * j];
        }
        __syncthreads();
    }
}

// ---------- St[b][d][m] = bf16(sum_split Spart) ----------
__global__ __launch_bounds__(256) void s_fin(const float* __restrict__ Sp,
                                             ushort* __restrict__ St) {
    __shared__ ushort lds[64 * 78];
    const int t = threadIdx.x;
    const int mt = blockIdx.x, dt = blockIdx.y, b = blockIdx.z;
    {
        const int r = t >> 2, c0 = (t & 3) * 16;
        float accv[16];
#pragma unroll
        for (int j = 0; j < 16; ++j) accv[j] = 0.f;
#pragma unroll
        for (int sp = 0; sp < NSPLIT; ++sp) {
            const float4* src = (const float4*)(Sp +
                ((size_t)(sp * BB + b) * MM + mt * 64 + r) * DD + dt * 64 + c0);
#pragma unroll
            for (int i = 0; i < 4; ++i) {
                float4 v = src[i];
                accv[4 * i + 0] += v.x; accv[4 * i + 1] += v.y;
                accv[4 * i + 2] += v.z; accv[4 * i + 3] += v.w;
            }
        }
#pragma unroll
        for (int j = 0; j < 16; ++j) lds[r * 78 + c0 + j] = f2b(accv[j]);
    }
    __syncthreads();
    {
        const int d = t >> 2, m0 = (t & 3) * 16;
        ushort* dst = St + ((size_t)b * DD + dt * 64 + d) * MM + mt * 64 + m0;
#pragma unroll
        for (int j = 0; j < 16; ++j) dst[j] = lds[(m0 + j) * 78 + d];
    }
}

// ---------- den[lg] = phi_q[lg,:] . Z[b,:] ----------
__global__ __launch_bounds__(256) void den_kernel(const ushort* __restrict__ PhiQ,
                                                  const float* __restrict__ Z,
                                                  float* __restrict__ Den) {
    const int row = blockIdx.x * 4 + (threadIdx.x >> 6);
    const int lane = threadIdx.x & 63;
    const int b = row >> 11;
    s16x4 q = *(const s16x4*)(PhiQ + (size_t)row * MM + lane * 4);
    float4 z = *(const float4*)(Z + (size_t)b * MM + lane * 4);
    float s = b2f((ushort)q[0]) * z.x + b2f((ushort)q[1]) * z.y +
              b2f((ushort)q[2]) * z.z + b2f((ushort)q[3]) * z.w;
#pragma unroll
    for (int off = 32; off; off >>= 1) s += __shfl_down(s, off);
    if (lane == 0) Den[row] = s;
}

// ---------- out GEMM + divide + residual (XCD-swizzled 1-D grid 512) ----------
__global__ __launch_bounds__(256) void out_gemm(const ushort* __restrict__ PhiQ,
                                                const ushort* __restrict__ St,
                                                const float* __restrict__ Den,
                                                const float* __restrict__ Content,
                                                float* __restrict__ Amp,
                                                float* __restrict__ Fa) {
    __shared__ __align__(16) ushort smem[128 * 64];
    ushort* sA = smem;
    ushort* sB = smem + 128 * 32;
    f32x4 acc[4][4] = {};
    const int z = blockIdx.x;
    const int xcd = z & 7, slot = z >> 3;
    const int g = xcd * 8 + (slot >> 3);
    const int b = g >> 3, lpair = g & 7;
    const int lt = lpair * 2 + ((slot >> 2) & 1);
    const int rowbase = lt * 128;                 // l local
    const int colbase = (slot & 3) * 128;         // d
    const ushort* A = PhiQ + (size_t)b * LL * MM;
    const ushort* B = St + (size_t)b * DD * MM;
    gemm128(A, MM, B, MM, rowbase, colbase, 0, MM, sA, sB, acc);

    const int t = threadIdx.x, l = t & 63, w = t >> 6;
    const int wr = (w >> 1) * 64, wc = (w & 1) * 64, fr = l & 15, fg = l >> 4;
    float* ldsf = (float*)smem;

    for (int c = 0; c < 4; ++c) {
        const bool part = (wr == 0) ? (c < 2) : (c >= 2);
        const int c2 = (wr == 0) ? c : c - 2;
        if (part) {
#pragma unroll
            for (int mi2 = 0; mi2 < 2; ++mi2) {
                const int mi = 2 * c2 + mi2;
#pragma unroll
                for (int ni = 0; ni < 4; ++ni)
#pragma unroll
                    for (int rr = 0; rr < 4; ++rr)
                        ldsf[(mi2 * 16 + fg * 4 + rr) * 128 + wc + ni * 16 + fr] =
                            acc[mi][ni][rr];
            }
        }
        __syncthreads();
        {
            const int row = t >> 3, col0 = (t & 7) * 16;
            const int lg = b * LL + rowbase + c * 32 + row;
            const float inv = 1.0f / (Den[lg] + EPSV);
            const size_t base = (size_t)lg * DD + colbase + col0;
#pragma unroll
            for (int j = 0; j < 4; ++j) {
                float4 v = *(float4*)&ldsf[row * 128 + col0 + 4 * j];
                float4 f4 = {v.x * inv, v.y * inv, v.z * inv, v.w * inv};
                float4 c4 = *(const float4*)&Content[base + 4 * j];
                *(float4*)&Fa[base + 4 * j] = f4;
                float4 a4 = {c4.x + f4.x, c4.y + f4.y, c4.z + f4.z, c4.w + f4.w};
                *(float4*)&Amp[base + 4 * j] = a4;
            }
        }
        __syncthreads();
    }
}

extern "C" void kernel_launch(void* const* d_in, const int* in_sizes, int n_in,
                              void* d_out, int out_size, void* d_ws, size_t ws_size,
                              hipStream_t stream) {
    const float* content = (const float*)d_in[0];   // [8,2048,512]
    const float* style   = (const float*)d_in[1];   // [8,4,2048,512]
    const float* Wm      = (const float*)d_in[2];   // [512,256]
    float* amp = (float*)d_out;
    float* fa  = (float*)d_out + (size_t)BB * LL * DD;

    // styleT (bf16, [b][d][kl], 67 MB) lives in d_out — scratch until out_gemm.
    ushort* styleT = (ushort*)d_out;

    // ---- workspace layout ----
    float* wsf   = (float*)d_ws;
    float* Spart = wsf;                                   // 32 MB
    float* sq_k  = Spart + (size_t)NSPLIT * BB * MM * DD;
    float* sq_q  = sq_k + (size_t)BB * KLT;
    float* Zbuf  = sq_q + (size_t)BB * LL;
    float* den   = Zbuf + (size_t)BB * MM;
    ushort* wsu     = (ushort*)(den + (size_t)BB * LL);
    ushort* style_b = wsu;                                 // 67 MB
    ushort* cont_b  = style_b + (size_t)BB * KLT * DD;
    ushort* Wt      = cont_b + (size_t)BB * LL * DD;
    ushort* phi_kT  = Wt + (size_t)MM * DD;
    ushort* phi_q   = phi_kT + (size_t)BB * MM * KLT;
    ushort* St      = phi_q + (size_t)BB * LL * MM;

    hipMemsetAsync(Zbuf, 0, (size_t)BB * MM * sizeof(float), stream);

    prep_w<<<dim3(8, 4), 256, 0, stream>>>(Wm, Wt);
    convert_rows<<<(BB * LL) / 4, 256, 0, stream>>>(content, cont_b, sq_q);
    conv_style<<<dim3(KLT / 64, BB), 256, 0, stream>>>(style, style_b, styleT, sq_k);

    phikt_gemm<<<1024, 256, 0, stream>>>(Wt, style_b, sq_k, phi_kT, Zbuf);
    phiq_gemm<<<256, 256, 0, stream>>>(cont_b, Wt, sq_q, phi_q);

    s_gemm<<<512, 256, 0, stream>>>(phi_kT, styleT, Spart);
    s_fin<<<dim3(MM / 64, DD / 64, BB), 256, 0, stream>>>(Spart, St);

    den_kernel<<<(BB * LL) / 4, 256, 0, stream>>>(phi_q, Zbuf, den);
    out_gemm<<<512, 256, 0, stream>>>(phi_q, St, den, content, amp, fa);
}